// Round 15
// baseline (606.199 us; speedup 1.0000x reference)
//
#include <hip/hip_runtime.h>
#include <cstddef>
#include <cstdint>

// ---------------------------------------------------------------------------
// STSN forward, v13 = v12 + two-image pipelined dec3 (k_conv_pipe):
// double-buffered LDS, issue-early/write-late staging so img(i+1)'s global
// loads fly under img(i)'s MFMA compute (T14). dec2/encoder keep v12 path.
// B=32, H=W=80, C=32, S=9, ITERS=3
// ---------------------------------------------------------------------------

namespace {

constexpr int Bb  = 32;
constexpr int HWp = 6400;
constexpr float SCALEf = 0.17677669529663687f;  // 32^-0.5

// output section offsets (floats)
constexpr size_t O_COMB  = 0;
constexpr size_t O_RECON = 204800;
constexpr size_t O_MASK  = 2048000;
constexpr size_t O_SLOTS = 3891200;
constexpr size_t O_ATTN  = 3900416;

// workspace layout (float offsets)
constexpr size_t W_PEENC = 0;                 // 204800 [hw][c] fp32
constexpr size_t W_PEDEC = 204800;            // 204800 [c][hw] fp32
constexpr size_t W_BASE  = 409600;            // 102400 (bf16 [hw][c])
constexpr size_t W_TC    = 512000;            // 25600
constexpr size_t W_TS    = 537600;            // 230400
constexpr size_t W_WP    = 768000;            // packed conv weights bf16
constexpr size_t W_WPM   = 844800;            // packed 32x32 matrices bf16
constexpr size_t W_LNPART= 846848;            // 1600
constexpr size_t W_MEANR = 848448;            // 64
constexpr size_t W_Q     = 848512;            // 9216
constexpr size_t W_SLOTS = 857728;            // 9216
constexpr size_t W_APART = 866944;            // 7200
constexpr size_t W_RSUM  = 874144;            // 288
constexpr size_t W_UP2   = 874432;            // 230400
constexpr size_t W_KEYS  = 1104832;           // 3276800 (bf16 [b][hw][c])
constexpr size_t W_VALS  = 4381632;           // 3276800 (bf16)
constexpr size_t W_POOL  = 7658432;           // 21456896 floats available
constexpr size_t W_TOTAL = 29115328;          // 116.5 MB
// Pool aliasing: E1/E2 (encoder) | attnt (attention) | XA/XB (decoder)

typedef __attribute__((ext_vector_type(8))) short short8;
typedef __attribute__((ext_vector_type(4))) float f32x4;

__device__ __forceinline__ ushort f2bf(float f) {
  uint u = __builtin_bit_cast(uint, f);
  uint r = (u + 0x7fffu + ((u >> 16) & 1u)) >> 16;   // RNE
  return (ushort)r;
}
__device__ __forceinline__ float bf2f(ushort b) {
  uint u = ((uint)b) << 16;
  return __builtin_bit_cast(float, u);
}
__device__ __forceinline__ void unpk2(uint w, float& a, float& b) {
  a = __builtin_bit_cast(float, w << 16);
  b = __builtin_bit_cast(float, w & 0xffff0000u);
}

__device__ __forceinline__ float lane_ln(float v, int o, const float* __restrict__ g,
                                         const float* __restrict__ b) {
  float s = v;
#pragma unroll
  for (int m = 16; m >= 1; m >>= 1) s += __shfl_xor(s, m);
  float mean = s * (1.f / 32.f);
  float d = v - mean;
  float q = d * d;
#pragma unroll
  for (int m = 16; m >= 1; m >>= 1) q += __shfl_xor(q, m);
  float rstd = rsqrtf(q * (1.f / 32.f) + 1e-5f);
  return d * rstd * g[o] + b[o];
}

// ---------------- positional-embedding maps ---------------------------------

__global__ void k_pe_maps(const float* __restrict__ pew_e, const float* __restrict__ peb_e,
                          const float* __restrict__ pew_d, const float* __restrict__ peb_d,
                          float* __restrict__ pe_enc, float* __restrict__ pe_dec) {
  int hw = blockIdx.x * 256 + threadIdx.x;
  if (hw >= HWp) return;
  int y = hw / 80, x = hw % 80;
  float g0 = y * (1.f / 79.f), g1 = x * (1.f / 79.f);
  float g2 = 1.f - g0, g3 = 1.f - g1;
#pragma unroll
  for (int c = 0; c < 32; ++c) {
    pe_enc[(size_t)hw * 32 + c] = peb_e[c] + g0 * pew_e[c * 4] + g1 * pew_e[c * 4 + 1] +
                                  g2 * pew_e[c * 4 + 2] + g3 * pew_e[c * 4 + 3];
    pe_dec[(size_t)c * HWp + hw] = peb_d[c] + g0 * pew_d[c * 4] + g1 * pew_d[c * 4 + 1] +
                                   g2 * pew_d[c * 4 + 2] + g3 * pew_d[c * 4 + 3];
  }
}

// ---------------- weight packing -------------------------------------------

__global__ void k_pack(const float* __restrict__ w, ushort* __restrict__ dst, int trans) {
  int tap = blockIdx.x;
  int grp = threadIdx.x >> 6, lane = threadIdx.x & 63;
  int ky = tap / 5, kx = tap % 5;
  int m = grp * 16 + (lane & 15);
  int kb = (lane >> 4) * 8;
  ushort* o = dst + ((size_t)(tap * 2 + grp) * 64 + lane) * 8;
#pragma unroll
  for (int j = 0; j < 8; ++j) {
    int k = kb + j;
    float v = trans ? w[(size_t)k * 800 + m * 25 + (4 - ky) * 5 + (4 - kx)]
                    : w[(size_t)m * 800 + k * 25 + ky * 5 + kx];
    o[j] = f2bf(v);
  }
}

// pack a row-major [32][32] matrix (y = x @ W^T form, A[m=o][k=c]) into A-frags
__global__ void k_pack_mat(const float* __restrict__ w, ushort* __restrict__ dst) {
  int grp = threadIdx.x >> 6, lane = threadIdx.x & 63;   // 128 threads
  int m = grp * 16 + (lane & 15), kb = (lane >> 4) * 8;
  ushort* o = dst + ((size_t)(grp * 64 + lane)) * 8;
#pragma unroll
  for (int j = 0; j < 8; ++j) o[j] = f2bf(w[m * 32 + kb + j]);
}

// ---------------- Tc / Ts for algebraic decoder conv1 ------------------------

__global__ void k_prep_tc(const float* __restrict__ w, float* __restrict__ tc) {
  const int rep[5] = {0, 1, 40, 78, 79};
  int cls = blockIdx.x;
  int yc = cls / 5, xc = cls % 5;
  int ci = threadIdx.x >> 5, co = threadIdx.x & 31;
  int yr = rep[yc], xr = rep[xc];
  float s = 0.f;
#pragma unroll
  for (int ky = 0; ky < 5; ++ky) {
    if ((unsigned)(yr + ky - 2) >= 80u) continue;
#pragma unroll
    for (int kx = 0; kx < 5; ++kx) {
      if ((unsigned)(xr + kx - 2) >= 80u) continue;
      s += w[(size_t)ci * 800 + co * 25 + (4 - ky) * 5 + (4 - kx)];
    }
  }
  tc[(size_t)cls * 1024 + ci * 32 + co] = s;
}

__global__ void k_ts(const float* __restrict__ tc, const float* __restrict__ slots,
                     float* __restrict__ ts) {
  int idx = blockIdx.x * 256 + threadIdx.x;
  if (idx >= 288 * 800) return;
  int img = idx / 800, rem = idx % 800;
  int cls = rem >> 5, o = rem & 31;
  float s = 0.f;
#pragma unroll
  for (int ci = 0; ci < 32; ++ci)
    s += tc[(size_t)cls * 1024 + ci * 32 + o] * slots[(size_t)img * 32 + ci];
  ts[idx] = s;
}

// ---------------- MFMA conv (32->32, 5x5, pad 2), 16x16 tile -----------------
// MODE 0: fp32 channel-major input (base precompute). MODE 1: bf16 chlast.
// MODE 2: relu(base[hw][c] + ts[n0+img][cls(hw)][c]) fused dec1.

template <int MODE, bool RELU>
__global__ __launch_bounds__(256, 4) void k_conv_mfma(
    const void* __restrict__ in_, const ushort* __restrict__ wp,
    const float* __restrict__ bias, ushort* __restrict__ out_,
    const float* __restrict__ ts, int n0) {
  __shared__ int4 sm[1600];  // 20 rows * 20 px * 4 units of 16B
  const int n = blockIdx.y;
  const int ty = blockIdx.x / 5, tx = blockIdx.x % 5;
  const int t = threadIdx.x;

  for (int i = t; i < 1600; i += 256) {
    int u = i & 3, px = i >> 2;       // px 0..399
    int x = px % 20, r = px / 20;
    int gy = ty * 16 + r - 2, gx = tx * 16 + x - 2;
    int4 pk = {0, 0, 0, 0};
    if ((unsigned)gy < 80u && (unsigned)gx < 80u) {
      int hw = gy * 80 + gx;
      if constexpr (MODE == 0) {
        const float* fp = (const float*)in_;
        ushort bb[8];
#pragma unroll
        for (int j = 0; j < 8; ++j)
          bb[j] = f2bf(fp[(size_t)(u * 8 + j) * HWp + hw]);
        pk.x = (int)((uint)bb[0] | ((uint)bb[1] << 16));
        pk.y = (int)((uint)bb[2] | ((uint)bb[3] << 16));
        pk.z = (int)((uint)bb[4] | ((uint)bb[5] << 16));
        pk.w = (int)((uint)bb[6] | ((uint)bb[7] << 16));
      } else if constexpr (MODE == 1) {
        pk = *(const int4*)((const ushort*)in_ + ((size_t)n * HWp + hw) * 32 + u * 8);
      } else {
        int4 bp = *(const int4*)((const ushort*)in_ + (size_t)hw * 32 + u * 8);
        int yc = gy < 2 ? gy : (gy > 77 ? gy - 75 : 2);
        int xc = gx < 2 ? gx : (gx > 77 ? gx - 75 : 2);
        const float* tp = ts + ((size_t)(n0 + n) * 25 + (yc * 5 + xc)) * 32 + u * 8;
        float t0, t1;
        uint* pw = (uint*)&pk;
        const uint* bw = (const uint*)&bp;
#pragma unroll
        for (int h = 0; h < 4; ++h) {
          unpk2(bw[h], t0, t1);
          float f0 = fmaxf(t0 + tp[2 * h], 0.f);
          float f1 = fmaxf(t1 + tp[2 * h + 1], 0.f);
          pw[h] = (uint)f2bf(f0) | ((uint)f2bf(f1) << 16);
        }
      }
    }
    int up = u ^ ((x >> 1) & 3);
    sm[(r * 20 + x) * 4 + up] = pk;
  }
  __syncthreads();

  const int wv = t >> 6, lane = t & 63;
  const int l15 = lane & 15, lg = lane >> 4;
  const short8* smS = (const short8*)sm;

  f32x4 acc[4][2];
#pragma unroll
  for (int o = 0; o < 4; ++o)
#pragma unroll
    for (int c = 0; c < 2; ++c) acc[o][c] = f32x4{0.f, 0.f, 0.f, 0.f};

#pragma unroll
  for (int dx = 0; dx < 5; ++dx) {
    short8 Adx[5][2];
#pragma unroll
    for (int dy = 0; dy < 5; ++dy) {
      int tap = dy * 5 + dx;
      Adx[dy][0] = *(const short8*)(wp + ((size_t)(tap * 2 + 0) * 64 + lane) * 8);
      Adx[dy][1] = *(const short8*)(wp + ((size_t)(tap * 2 + 1) * 64 + lane) * 8);
    }
    const int xx = l15 + dx;
    const int us = lg ^ ((xx >> 1) & 3);
#pragma unroll
    for (int r8 = 0; r8 < 8; ++r8) {   // r8 = o + dy, valid range 0..7
      short8 Bv = smS[((wv * 4 + r8) * 20 + xx) * 4 + us];
#pragma unroll
      for (int o = 0; o < 4; ++o) {
        int dy = r8 - o;
        if (dy < 0 || dy > 4) continue;
        acc[o][0] = __builtin_amdgcn_mfma_f32_16x16x32_bf16(Adx[dy][0], Bv, acc[o][0], 0, 0, 0);
        acc[o][1] = __builtin_amdgcn_mfma_f32_16x16x32_bf16(Adx[dy][1], Bv, acc[o][1], 0, 0, 0);
      }
    }
  }

  float bv[2][4];
#pragma unroll
  for (int cg = 0; cg < 2; ++cg)
#pragma unroll
    for (int q = 0; q < 4; ++q) bv[cg][q] = bias[cg * 16 + lg * 4 + q];
  const int ybase = ty * 16 + wv * 4, xbase = tx * 16 + l15;
#pragma unroll
  for (int o = 0; o < 4; ++o) {
    size_t px = (size_t)n * HWp + (ybase + o) * 80 + xbase;
#pragma unroll
    for (int cg = 0; cg < 2; ++cg) {
      f32x4 v = acc[o][cg];
      float o0 = v[0] + bv[cg][0], o1 = v[1] + bv[cg][1];
      float o2 = v[2] + bv[cg][2], o3 = v[3] + bv[cg][3];
      if (RELU) {
        o0 = fmaxf(o0, 0.f); o1 = fmaxf(o1, 0.f);
        o2 = fmaxf(o2, 0.f); o3 = fmaxf(o3, 0.f);
      }
      uint2 pk;
      pk.x = (uint)f2bf(o0) | ((uint)f2bf(o1) << 16);
      pk.y = (uint)f2bf(o2) | ((uint)f2bf(o3) << 16);
      *(uint2*)(out_ + px * 32 + cg * 16 + lg * 4) = pk;
    }
  }
}

// ---------------- two-image pipelined conv (MODE 1 path, dec3) ---------------
// Double-buffered LDS (51.2 KB, 3 blocks/CU). Image pair per block:
// stage(img0) | barrier | issue-loads(img1) -> compute+store(img0) ->
// ds_write(img1) | barrier | compute+store(img1).  Loads for img1 fly under
// img0's MFMA compute (issue-early/write-late). Per-image math identical to
// k_conv_mfma<1,RELU> (bit-identical output).

template <bool RELU>
__global__ __launch_bounds__(256, 3) void k_conv_pipe(
    const ushort* __restrict__ in, const ushort* __restrict__ wp,
    const float* __restrict__ bias, ushort* __restrict__ out) {
  __shared__ int4 sm[2][1600];
  const int pr = blockIdx.y;                 // image pair index
  const int ty = blockIdx.x / 5, tx = blockIdx.x % 5;
  const int t = threadIdx.x;
  const int wv = t >> 6, lane = t & 63;
  const int l15 = lane & 15, lg = lane >> 4;

  auto load_img = [&](int bi, int4* rr) {
#pragma unroll
    for (int k = 0; k < 7; ++k) {
      int e = t + (k << 8);
      if (k < 6 || e < 1600) {
        int u = e & 3, px = e >> 2;
        int x = px % 20, r = px / 20;
        int gy = ty * 16 + r - 2, gx = tx * 16 + x - 2;
        int4 pk = {0, 0, 0, 0};
        if ((unsigned)gy < 80u && (unsigned)gx < 80u)
          pk = *(const int4*)(in + ((size_t)bi * HWp + gy * 80 + gx) * 32 + u * 8);
        rr[k] = pk;
      }
    }
  };
  auto write_sm = [&](int buf, const int4* rr) {
#pragma unroll
    for (int k = 0; k < 7; ++k) {
      int e = t + (k << 8);
      if (k < 6 || e < 1600) {
        int u = e & 3, px = e >> 2;
        int x = px % 20, r = px / 20;
        sm[buf][(r * 20 + x) * 4 + (u ^ ((x >> 1) & 3))] = rr[k];
      }
    }
  };
  auto compute_store = [&](int buf, int bi) {
    const short8* smS = (const short8*)sm[buf];
    f32x4 acc[4][2];
#pragma unroll
    for (int o = 0; o < 4; ++o)
#pragma unroll
      for (int c = 0; c < 2; ++c) acc[o][c] = f32x4{0.f, 0.f, 0.f, 0.f};
#pragma unroll
    for (int dx = 0; dx < 5; ++dx) {
      short8 Adx[5][2];
#pragma unroll
      for (int dy = 0; dy < 5; ++dy) {
        int tap = dy * 5 + dx;
        Adx[dy][0] = *(const short8*)(wp + ((size_t)(tap * 2 + 0) * 64 + lane) * 8);
        Adx[dy][1] = *(const short8*)(wp + ((size_t)(tap * 2 + 1) * 64 + lane) * 8);
      }
      const int xx = l15 + dx;
      const int us = lg ^ ((xx >> 1) & 3);
#pragma unroll
      for (int r8 = 0; r8 < 8; ++r8) {
        short8 Bv = smS[((wv * 4 + r8) * 20 + xx) * 4 + us];
#pragma unroll
        for (int o = 0; o < 4; ++o) {
          int dy = r8 - o;
          if (dy < 0 || dy > 4) continue;
          acc[o][0] = __builtin_amdgcn_mfma_f32_16x16x32_bf16(Adx[dy][0], Bv, acc[o][0], 0, 0, 0);
          acc[o][1] = __builtin_amdgcn_mfma_f32_16x16x32_bf16(Adx[dy][1], Bv, acc[o][1], 0, 0, 0);
        }
      }
    }
    float bvv[2][4];
#pragma unroll
    for (int cg = 0; cg < 2; ++cg)
#pragma unroll
      for (int q = 0; q < 4; ++q) bvv[cg][q] = bias[cg * 16 + lg * 4 + q];
    const int ybase = ty * 16 + wv * 4, xbase = tx * 16 + l15;
#pragma unroll
    for (int o = 0; o < 4; ++o) {
      size_t px = (size_t)bi * HWp + (ybase + o) * 80 + xbase;
#pragma unroll
      for (int cg = 0; cg < 2; ++cg) {
        f32x4 v = acc[o][cg];
        float o0 = v[0] + bvv[cg][0], o1 = v[1] + bvv[cg][1];
        float o2 = v[2] + bvv[cg][2], o3 = v[3] + bvv[cg][3];
        if (RELU) {
          o0 = fmaxf(o0, 0.f); o1 = fmaxf(o1, 0.f);
          o2 = fmaxf(o2, 0.f); o3 = fmaxf(o3, 0.f);
        }
        uint2 pk;
        pk.x = (uint)f2bf(o0) | ((uint)f2bf(o1) << 16);
        pk.y = (uint)f2bf(o2) | ((uint)f2bf(o3) << 16);
        *(uint2*)(out + px * 32 + cg * 16 + lg * 4) = pk;
      }
    }
  };

  int4 rr[7];
  load_img(pr * 2, rr);
  write_sm(0, rr);
  __syncthreads();
  load_img(pr * 2 + 1, rr);      // loads in flight under img0 compute
  compute_store(0, pr * 2);
  write_sm(1, rr);               // vmcnt waits land here, after compute
  __syncthreads();
  compute_store(1, pr * 2 + 1);
}

// ---------------- encoder conv1 ----------------------------------------------

__global__ __launch_bounds__(256) void k_conv1(const float* __restrict__ in,
                                               const float* __restrict__ w,
                                               const float* __restrict__ b,
                                               ushort* __restrict__ out) {
  int hw = blockIdx.x * 256 + threadIdx.x;
  int n = blockIdx.y;
  int y = hw / 80, x = hw % 80;
  float xv[25];
#pragma unroll
  for (int ky = 0; ky < 5; ++ky)
#pragma unroll
    for (int kx = 0; kx < 5; ++kx) {
      int iy = y + ky - 2, ix = x + kx - 2;
      xv[ky * 5 + kx] = ((unsigned)iy < 80u && (unsigned)ix < 80u)
                            ? in[(size_t)n * HWp + iy * 80 + ix] : 0.f;
    }
  float a[32];
#pragma unroll
  for (int co = 0; co < 32; ++co) {
    float s = b[co];
#pragma unroll
    for (int tp = 0; tp < 25; ++tp) s = fmaf(xv[tp], w[co * 25 + tp], s);
    a[co] = fmaxf(s, 0.f);
  }
  ushort* op = out + ((size_t)n * HWp + hw) * 32;
#pragma unroll
  for (int g = 0; g < 4; ++g) {
    uint4 pk;
    pk.x = (uint)f2bf(a[g * 8 + 0]) | ((uint)f2bf(a[g * 8 + 1]) << 16);
    pk.y = (uint)f2bf(a[g * 8 + 2]) | ((uint)f2bf(a[g * 8 + 3]) << 16);
    pk.z = (uint)f2bf(a[g * 8 + 4]) | ((uint)f2bf(a[g * 8 + 5]) << 16);
    pk.w = (uint)f2bf(a[g * 8 + 6]) | ((uint)f2bf(a[g * 8 + 7]) << 16);
    *(uint4*)(op + g * 8) = pk;
  }
}

// ---------------- decoder conv4 (32->2, 3x3, trans) --------------------------

__global__ __launch_bounds__(256) void k_conv4(const ushort* __restrict__ in,
                                               const float* __restrict__ w,
                                               const float* __restrict__ b,
                                               float* __restrict__ outR,
                                               float* __restrict__ outM, int n0) {
  __shared__ float sw[2 * 288];
  for (int e = threadIdx.x; e < 576; e += 256) {
    int co = e / 288, rem = e % 288;
    int tap = rem / 32, ci = rem % 32;
    sw[e] = w[(size_t)(ci * 2 + co) * 9 + 8 - tap];
  }
  __syncthreads();
  int hw = blockIdx.x * 256 + threadIdx.x;
  int nl = blockIdx.y;
  int y = hw / 80, x = hw % 80;
  float a0 = b[0], a1 = b[1];
  const ushort* ip = in + (size_t)nl * HWp * 32;
#pragma unroll
  for (int ky = 0; ky < 3; ++ky) {
#pragma unroll
    for (int kx = 0; kx < 3; ++kx) {
      int iy = y + ky - 1, ix = x + kx - 1;
      if ((unsigned)iy >= 80u || (unsigned)ix >= 80u) continue;
      int tap = ky * 3 + kx;
      const int4* p = (const int4*)(ip + (size_t)(iy * 80 + ix) * 32);
      const float* w0 = sw + tap * 32;
      const float* w1 = sw + 288 + tap * 32;
#pragma unroll
      for (int u = 0; u < 4; ++u) {
        int4 ch = p[u];
        const uint* cw = (const uint*)&ch;
#pragma unroll
        for (int h = 0; h < 4; ++h) {
          float v0, v1;
          unpk2(cw[h], v0, v1);
          int ci = u * 8 + h * 2;
          a0 = fmaf(v0, w0[ci], a0);     a1 = fmaf(v0, w1[ci], a1);
          a0 = fmaf(v1, w0[ci + 1], a0); a1 = fmaf(v1, w1[ci + 1], a1);
        }
      }
    }
  }
  outR[(size_t)(n0 + nl) * HWp + hw] = a0;
  outM[(size_t)(n0 + nl) * HWp + hw] = a1;
}

// ---------------- big-LN stats from E2+PE ------------------------------------

__global__ __launch_bounds__(256) void k_hstats(const ushort* __restrict__ enc,
                                                const float* __restrict__ pe_enc,
                                                float* __restrict__ lnpart) {
  int b = blockIdx.y;
  int hw = blockIdx.x * 256 + threadIdx.x;
  const int4* ep = (const int4*)(enc + ((size_t)b * HWp + hw) * 32);
  float v[32];
#pragma unroll
  for (int u = 0; u < 4; ++u) {
    int4 ch = ep[u];
    const uint* cw = (const uint*)&ch;
#pragma unroll
    for (int h = 0; h < 4; ++h) unpk2(cw[h], v[u * 8 + h * 2], v[u * 8 + h * 2 + 1]);
  }
  float s = 0.f, ss = 0.f;
#pragma unroll
  for (int c = 0; c < 32; ++c) {
    v[c] += pe_enc[(size_t)hw * 32 + c];
    s += v[c]; ss += v[c] * v[c];
  }
  __shared__ float r1[256], r2[256];
  r1[threadIdx.x] = s; r2[threadIdx.x] = ss;
  __syncthreads();
  for (int off = 128; off > 0; off >>= 1) {
    if (threadIdx.x < off) { r1[threadIdx.x] += r1[threadIdx.x + off]; r2[threadIdx.x] += r2[threadIdx.x + off]; }
    __syncthreads();
  }
  if (threadIdx.x == 0) {
    lnpart[(size_t)(b * 25 + blockIdx.x) * 2] = r1[0];
    lnpart[(size_t)(b * 25 + blockIdx.x) * 2 + 1] = r2[0];
  }
}

__global__ void k_statsfin(const float* __restrict__ lnpart, float* __restrict__ meanr) {
  int b = threadIdx.x;
  if (b >= 32) return;
  float s = 0.f, ss = 0.f;
  for (int k = 0; k < 25; ++k) {
    s += lnpart[(size_t)(b * 25 + k) * 2];
    ss += lnpart[(size_t)(b * 25 + k) * 2 + 1];
  }
  float m = s * (1.f / 204800.f);
  float var = ss * (1.f / 204800.f) - m * m;
  meanr[b * 2] = m;
  meanr[b * 2 + 1] = rsqrtf(var + 1e-5f);
}

// ---------------- MFMA lnmlpkv ----------------------------------------------

__global__ __launch_bounds__(256) void k_lnmlpkv_mfma(
    const ushort* __restrict__ enc, const float* __restrict__ pe,
    const float* __restrict__ meanr,
    const float* __restrict__ g, const float* __restrict__ bb,
    const ushort* __restrict__ wm,
    const float* __restrict__ b1, const float* __restrict__ b2,
    const float* __restrict__ nig, const float* __restrict__ nib,
    const float* __restrict__ kb, const float* __restrict__ vb,
    ushort* __restrict__ keys, ushort* __restrict__ vals) {
  __shared__ ushort ls[256 * 32];   // 16 KB bounce buffer
  const int b = blockIdx.y, jb = blockIdx.x;
  const int t = threadIdx.x, wv = t >> 6, lane = t & 63;
  const int l15 = lane & 15, lg = lane >> 4;
  const int skey = l15 & 3;

  short8 A[4][2];
#pragma unroll
  for (int mt = 0; mt < 4; ++mt)
#pragma unroll
    for (int gr = 0; gr < 2; ++gr)
      A[mt][gr] = *(const short8*)(wm + ((size_t)(mt * 2 + gr) * 64 + lane) * 8);

  float4 b1v0 = *(const float4*)(b1 + lg * 4),  b1v1 = *(const float4*)(b1 + 16 + lg * 4);
  float4 b2v0 = *(const float4*)(b2 + lg * 4),  b2v1 = *(const float4*)(b2 + 16 + lg * 4);
  float4 ng0  = *(const float4*)(nig + lg * 4), ng1  = *(const float4*)(nig + 16 + lg * 4);
  float4 nb0  = *(const float4*)(nib + lg * 4), nb1  = *(const float4*)(nib + 16 + lg * 4);
  float4 kbv0 = *(const float4*)(kb + lg * 4),  kbv1 = *(const float4*)(kb + 16 + lg * 4);
  float4 vbv0 = *(const float4*)(vb + lg * 4),  vbv1 = *(const float4*)(vb + 16 + lg * 4);

  const float m_ = meanr[b * 2], rs_ = meanr[b * 2 + 1];

  short8 bx[4];
#pragma unroll
  for (int g2 = 0; g2 < 4; ++g2) {
    int pos = jb * 256 + wv * 64 + g2 * 16 + l15;
    int4 e = *(const int4*)(enc + ((size_t)b * HWp + pos) * 32 + lg * 8);
    float xv[8];
    const uint* ew = (const uint*)&e;
#pragma unroll
    for (int h = 0; h < 4; ++h) unpk2(ew[h], xv[2 * h], xv[2 * h + 1]);
    float4 p0 = *(const float4*)(pe + (size_t)pos * 32 + lg * 8);
    float4 p1 = *(const float4*)(pe + (size_t)pos * 32 + lg * 8 + 4);
    float4 g0 = *(const float4*)(g + (size_t)pos * 32 + lg * 8);
    float4 g1 = *(const float4*)(g + (size_t)pos * 32 + lg * 8 + 4);
    float4 q0 = *(const float4*)(bb + (size_t)pos * 32 + lg * 8);
    float4 q1 = *(const float4*)(bb + (size_t)pos * 32 + lg * 8 + 4);
    float pv[8] = {p0.x, p0.y, p0.z, p0.w, p1.x, p1.y, p1.z, p1.w};
    float gv[8] = {g0.x, g0.y, g0.z, g0.w, g1.x, g1.y, g1.z, g1.w};
    float qv[8] = {q0.x, q0.y, q0.z, q0.w, q1.x, q1.y, q1.z, q1.w};
    uint pk[4];
#pragma unroll
    for (int h = 0; h < 4; ++h) {
      float f0 = (xv[2 * h] + pv[2 * h] - m_) * rs_ * gv[2 * h] + qv[2 * h];
      float f1 = (xv[2 * h + 1] + pv[2 * h + 1] - m_) * rs_ * gv[2 * h + 1] + qv[2 * h + 1];
      pk[h] = (uint)f2bf(f0) | ((uint)f2bf(f1) << 16);
    }
    bx[g2] = __builtin_bit_cast(short8, *(int4*)pk);
  }

  auto lds_write = [&](int posl, int cg, const f32x4& v) {
    int u = cg * 2 + (lg >> 1);
    int us = u ^ skey;
    uint2 pk;
    pk.x = (uint)f2bf(v[0]) | ((uint)f2bf(v[1]) << 16);
    pk.y = (uint)f2bf(v[2]) | ((uint)f2bf(v[3]) << 16);
    *(uint2*)(ls + (size_t)posl * 32 + us * 8 + (lg & 1) * 4) = pk;
  };

#pragma unroll
  for (int g2 = 0; g2 < 4; ++g2) {
    int posl = wv * 64 + g2 * 16 + l15;
    f32x4 a0 = __builtin_amdgcn_mfma_f32_16x16x32_bf16(A[0][0], bx[g2], f32x4{0, 0, 0, 0}, 0, 0, 0);
    f32x4 a1 = __builtin_amdgcn_mfma_f32_16x16x32_bf16(A[0][1], bx[g2], f32x4{0, 0, 0, 0}, 0, 0, 0);
    f32x4 r0, r1;
#pragma unroll
    for (int q = 0; q < 4; ++q) {
      r0[q] = fmaxf(a0[q] + (&b1v0.x)[q], 0.f);
      r1[q] = fmaxf(a1[q] + (&b1v1.x)[q], 0.f);
    }
    lds_write(posl, 0, r0);
    lds_write(posl, 1, r1);
  }
  __syncthreads();
  short8 t0f[4];
#pragma unroll
  for (int g2 = 0; g2 < 4; ++g2) {
    int posl = wv * 64 + g2 * 16 + l15;
    t0f[g2] = *(const short8*)(ls + (size_t)posl * 32 + (lg ^ skey) * 8);
  }
  __syncthreads();

#pragma unroll
  for (int g2 = 0; g2 < 4; ++g2) {
    int posl = wv * 64 + g2 * 16 + l15;
    f32x4 c0 = __builtin_amdgcn_mfma_f32_16x16x32_bf16(A[1][0], t0f[g2], f32x4{0, 0, 0, 0}, 0, 0, 0);
    f32x4 c1 = __builtin_amdgcn_mfma_f32_16x16x32_bf16(A[1][1], t0f[g2], f32x4{0, 0, 0, 0}, 0, 0, 0);
#pragma unroll
    for (int q = 0; q < 4; ++q) { c0[q] += (&b2v0.x)[q]; c1[q] += (&b2v1.x)[q]; }
    float s = 0.f;
#pragma unroll
    for (int q = 0; q < 4; ++q) s += c0[q] + c1[q];
    s += __shfl_xor(s, 16); s += __shfl_xor(s, 32);
    float mean = s * (1.f / 32.f);
    float var = 0.f;
#pragma unroll
    for (int q = 0; q < 4; ++q) {
      float d0 = c0[q] - mean, d1 = c1[q] - mean;
      var += d0 * d0 + d1 * d1;
    }
    var += __shfl_xor(var, 16); var += __shfl_xor(var, 32);
    float rstd = rsqrtf(var * (1.f / 32.f) + 1e-5f);
    f32x4 y0, y1;
#pragma unroll
    for (int q = 0; q < 4; ++q) {
      y0[q] = (c0[q] - mean) * rstd * (&ng0.x)[q] + (&nb0.x)[q];
      y1[q] = (c1[q] - mean) * rstd * (&ng1.x)[q] + (&nb1.x)[q];
    }
    lds_write(posl, 0, y0);
    lds_write(posl, 1, y1);
  }
  __syncthreads();
  short8 xnf[4];
#pragma unroll
  for (int g2 = 0; g2 < 4; ++g2) {
    int posl = wv * 64 + g2 * 16 + l15;
    xnf[g2] = *(const short8*)(ls + (size_t)posl * 32 + (lg ^ skey) * 8);
  }

#pragma unroll
  for (int g2 = 0; g2 < 4; ++g2) {
    int pos = jb * 256 + wv * 64 + g2 * 16 + l15;
    size_t px = ((size_t)b * HWp + pos) * 32;
    f32x4 k0 = __builtin_amdgcn_mfma_f32_16x16x32_bf16(A[2][0], xnf[g2], f32x4{0, 0, 0, 0}, 0, 0, 0);
    f32x4 k1 = __builtin_amdgcn_mfma_f32_16x16x32_bf16(A[2][1], xnf[g2], f32x4{0, 0, 0, 0}, 0, 0, 0);
    f32x4 v0 = __builtin_amdgcn_mfma_f32_16x16x32_bf16(A[3][0], xnf[g2], f32x4{0, 0, 0, 0}, 0, 0, 0);
    f32x4 v1 = __builtin_amdgcn_mfma_f32_16x16x32_bf16(A[3][1], xnf[g2], f32x4{0, 0, 0, 0}, 0, 0, 0);
    uint2 pk;
    pk.x = (uint)f2bf(k0[0] + kbv0.x) | ((uint)f2bf(k0[1] + kbv0.y) << 16);
    pk.y = (uint)f2bf(k0[2] + kbv0.z) | ((uint)f2bf(k0[3] + kbv0.w) << 16);
    *(uint2*)(keys + px + lg * 4) = pk;
    pk.x = (uint)f2bf(k1[0] + kbv1.x) | ((uint)f2bf(k1[1] + kbv1.y) << 16);
    pk.y = (uint)f2bf(k1[2] + kbv1.z) | ((uint)f2bf(k1[3] + kbv1.w) << 16);
    *(uint2*)(keys + px + 16 + lg * 4) = pk;
    pk.x = (uint)f2bf(v0[0] + vbv0.x) | ((uint)f2bf(v0[1] + vbv0.y) << 16);
    pk.y = (uint)f2bf(v0[2] + vbv0.z) | ((uint)f2bf(v0[3] + vbv0.w) << 16);
    *(uint2*)(vals + px + lg * 4) = pk;
    pk.x = (uint)f2bf(v1[0] + vbv1.x) | ((uint)f2bf(v1[1] + vbv1.y) << 16);
    pk.y = (uint)f2bf(v1[2] + vbv1.z) | ((uint)f2bf(v1[3] + vbv1.w) << 16);
    *(uint2*)(vals + px + 16 + lg * 4) = pk;
  }
}

// ---------------- slot attention -------------------------------------------

__global__ __launch_bounds__(256) void k_init_q(
    const float* __restrict__ mu, const float* __restrict__ sig,
    const float* __restrict__ noise,
    const float* __restrict__ nsg, const float* __restrict__ nsb,
    const float* __restrict__ qw, const float* __restrict__ qb,
    float* __restrict__ slots, float* __restrict__ qbuf) {
  int rl = threadIdx.x >> 5, o = threadIdx.x & 31;
  int r = blockIdx.x * 8 + rl;
  float s = mu[o] + sig[o] * noise[(size_t)r * 32 + o];
  slots[(size_t)r * 32 + o] = s;
  float y = lane_ln(s, o, nsg, nsb);
  __shared__ float S[8][32];
  S[rl][o] = y;
  __syncthreads();
  float qv = qb[o];
#pragma unroll
  for (int c = 0; c < 32; ++c) qv = fmaf(S[rl][c], qw[o * 32 + c], qv);
  qbuf[(size_t)r * 32 + o] = qv;
}

template <bool LAST>
__global__ __launch_bounds__(256) void k_dots_upd(
    const float* __restrict__ qbuf, const ushort* __restrict__ keys,
    const ushort* __restrict__ vals, float* __restrict__ attnt,
    float* __restrict__ apart, float* __restrict__ up2) {
  int b = blockIdx.y, jb = blockIdx.x;
  int t = threadIdx.x;
  int j = jb * 256 + t;
  __shared__ float qs[288];
  __shared__ float aL[2304];
  __shared__ float wr[36];
  for (int e = t; e < 288; e += 256) qs[e] = qbuf[(size_t)b * 288 + e];
  __syncthreads();
  float k[32];
  const int4* kp = (const int4*)(keys + ((size_t)b * HWp + j) * 32);
#pragma unroll
  for (int u = 0; u < 4; ++u) {
    int4 ch = kp[u];
    const uint* cw = (const uint*)&ch;
#pragma unroll
    for (int h = 0; h < 4; ++h) unpk2(cw[h], k[u * 8 + h * 2], k[u * 8 + h * 2 + 1]);
  }
  float d[9];
#pragma unroll
  for (int i = 0; i < 9; ++i) {
    float a = 0.f;
#pragma unroll
    for (int c = 0; c < 32; ++c) a = fmaf(qs[i * 32 + c], k[c], a);
    d[i] = a * SCALEf;
  }
  float mx = d[0];
#pragma unroll
  for (int i = 1; i < 9; ++i) mx = fmaxf(mx, d[i]);
  float sum = 0.f;
#pragma unroll
  for (int i = 0; i < 9; ++i) { d[i] = __expf(d[i] - mx); sum += d[i]; }
  float inv = 1.f / sum;
  float a9[9];
#pragma unroll
  for (int i = 0; i < 9; ++i) {
    a9[i] = d[i] * inv + 1e-8f;
    if (LAST) attnt[((size_t)b * 9 + i) * HWp + j] = a9[i];
    aL[t * 9 + i] = a9[i];
  }
  int lane = t & 63, wid = t >> 6;
#pragma unroll
  for (int i = 0; i < 9; ++i) {
    float v = a9[i];
    for (int off = 32; off > 0; off >>= 1) v += __shfl_down(v, off);
    if (lane == 0) wr[wid * 9 + i] = v;
  }
  __syncthreads();
  if (t < 9)
    apart[(size_t)(b * 9 + t) * 25 + jb] = wr[t] + wr[9 + t] + wr[18 + t] + wr[27 + t];
  int c = t & 31, g = t >> 5;
  float acc[9];
#pragma unroll
  for (int i = 0; i < 9; ++i) acc[i] = 0.f;
  const ushort* vp = vals + ((size_t)b * HWp + jb * 256) * 32 + c;
  for (int jj = g; jj < 256; jj += 8) {
    float v = bf2f(vp[(size_t)jj * 32]);
#pragma unroll
    for (int i = 0; i < 9; ++i) acc[i] = fmaf(v, aL[jj * 9 + i], acc[i]);
  }
  __syncthreads();
#pragma unroll
  for (int i = 0; i < 9; ++i) aL[(i * 8 + g) * 32 + c] = acc[i];
  __syncthreads();
  for (int i = g; i < 9; i += 8) {
    float s = 0.f;
#pragma unroll
    for (int g2 = 0; g2 < 8; ++g2) s += aL[(i * 8 + g2) * 32 + c];
    up2[(((size_t)b * 25 + jb) * 9 + i) * 32 + c] = s;
  }
}

__global__ __launch_bounds__(256) void k_gru_fused(
    const float* __restrict__ up2, const float* __restrict__ apart,
    float* __restrict__ slots, float* __restrict__ rowsum, float* __restrict__ qbuf,
    const float* __restrict__ wih, const float* __restrict__ whh,
    const float* __restrict__ bih, const float* __restrict__ bhh,
    const float* __restrict__ rlg, const float* __restrict__ rlb,
    const float* __restrict__ rw1, const float* __restrict__ rb1,
    const float* __restrict__ rw2, const float* __restrict__ rb2,
    const float* __restrict__ nsg, const float* __restrict__ nsb,
    const float* __restrict__ qw, const float* __restrict__ qb) {
  int rl = threadIdx.x >> 5, o = threadIdx.x & 31;
  int r = blockIdx.x * 8 + rl;
  int b = r / 9, i = r - b * 9;

  float rs = 0.f;
#pragma unroll
  for (int k = 0; k < 25; ++k) rs += apart[(size_t)(b * 9 + i) * 25 + k];
  if (o == 0) rowsum[r] = rs;

  float uo = 0.f;
#pragma unroll
  for (int jc = 0; jc < 25; ++jc) uo += up2[(((size_t)b * 25 + jc) * 9 + i) * 32 + o];
  uo /= rs;
  float ho = slots[(size_t)r * 32 + o];

  __shared__ float Us[8][32], Hs[8][32];
  Us[rl][o] = uo; Hs[rl][o] = ho;
  __syncthreads();

  float xr = bih[o], xz = bih[32 + o], xc = bih[64 + o];
  float hr = bhh[o], hz = bhh[32 + o], hc = bhh[64 + o];
#pragma unroll
  for (int c = 0; c < 32; ++c) {
    float u = Us[rl][c], h = Hs[rl][c];
    xr = fmaf(u, wih[o * 32 + c], xr);          hr = fmaf(h, whh[o * 32 + c], hr);
    xz = fmaf(u, wih[(32 + o) * 32 + c], xz);   hz = fmaf(h, whh[(32 + o) * 32 + c], hz);
    xc = fmaf(u, wih[(64 + o) * 32 + c], xc);   hc = fmaf(h, whh[(64 + o) * 32 + c], hc);
  }
  float rr = 1.f / (1.f + __expf(-(xr + hr)));
  float zz = 1.f / (1.f + __expf(-(xz + hz)));
  float cand = tanhf(xc + rr * hc);
  float sm = (1.f - zz) * cand + zz * ho;

  float y = lane_ln(sm, o, rlg, rlb);
  __syncthreads();
  Us[rl][o] = y;
  __syncthreads();
  float t1 = rb1[o];
#pragma unroll
  for (int c = 0; c < 32; ++c) t1 = fmaf(Us[rl][c], rw1[o * 32 + c], t1);
  t1 = fmaxf(t1, 0.f);
  Hs[rl][o] = t1;
  __syncthreads();
  float res = rb2[o];
#pragma unroll
  for (int c = 0; c < 32; ++c) res = fmaf(Hs[rl][c], rw2[o * 32 + c], res);
  float ns = sm + res;
  slots[(size_t)r * 32 + o] = ns;

  float y2 = lane_ln(ns, o, nsg, nsb);
  __syncthreads();
  Us[rl][o] = y2;
  __syncthreads();
  float qv = qb[o];
#pragma unroll
  for (int c = 0; c < 32; ++c) qv = fmaf(Us[rl][c], qw[o * 32 + c], qv);
  qbuf[(size_t)r * 32 + o] = qv;
}

// ---------------- outputs ----------------------------------------------------

__global__ void k_attn_out(const float* __restrict__ attnt, const float* __restrict__ rsum,
                           float* __restrict__ out) {
  size_t idx = (size_t)blockIdx.x * 256 + threadIdx.x;
  out[O_ATTN + idx] = attnt[idx] / rsum[idx / HWp];
}

__global__ void k_slots_out(const float* __restrict__ slots, float* __restrict__ out) {
  int idx = blockIdx.x * 256 + threadIdx.x;
  if (idx < 9216) out[O_SLOTS + idx] = slots[idx];
}

__global__ __launch_bounds__(256) void k_final(float* __restrict__ out) {
  int b = blockIdx.y;
  int j = blockIdx.x * 256 + threadIdx.x;
  float r[9], ml[9];
#pragma unroll
  for (int s = 0; s < 9; ++s) {
    r[s]  = out[O_RECON + (size_t)(b * 9 + s) * HWp + j];
    ml[s] = out[O_MASK  + (size_t)(b * 9 + s) * HWp + j];
  }
  float mx = ml[0];
#pragma unroll
  for (int s = 1; s < 9; ++s) mx = fmaxf(mx, ml[s]);
  float sum = 0.f;
#pragma unroll
  for (int s = 0; s < 9; ++s) { ml[s] = __expf(ml[s] - mx); sum += ml[s]; }
  float inv = 1.f / sum;
  float comb = 0.f;
#pragma unroll
  for (int s = 0; s < 9; ++s) {
    float mk = ml[s] * inv;
    comb = fmaf(r[s], mk, comb);
    out[O_MASK + (size_t)(b * 9 + s) * HWp + j] = mk;
  }
  out[O_COMB + (size_t)b * HWp + j] = comb;
}

}  // namespace

// ---------------------------------------------------------------------------

extern "C" void kernel_launch(void* const* d_in, const int* in_sizes, int n_in,
                              void* d_out, int out_size, void* d_ws, size_t ws_size,
                              hipStream_t stream) {
  if (ws_size < W_TOTAL * sizeof(float)) return;

  const float* in_x       = (const float*)d_in[0];
  const float* slot_noise = (const float*)d_in[1];
  const float* enc_w1 = (const float*)d_in[2];   const float* enc_b1 = (const float*)d_in[3];
  const float* enc_w2 = (const float*)d_in[4];   const float* enc_b2 = (const float*)d_in[5];
  const float* enc_w3 = (const float*)d_in[6];   const float* enc_b3 = (const float*)d_in[7];
  const float* enc_w4 = (const float*)d_in[8];   const float* enc_b4 = (const float*)d_in[9];
  const float* pe_enc_w = (const float*)d_in[10]; const float* pe_enc_b = (const float*)d_in[11];
  const float* ln_enc_g = (const float*)d_in[12]; const float* ln_enc_b = (const float*)d_in[13];
  const float* mlp_w1 = (const float*)d_in[14];  const float* mlp_b1 = (const float*)d_in[15];
  const float* mlp_w2 = (const float*)d_in[16];  const float* mlp_b2 = (const float*)d_in[17];
  const float* slots_mu = (const float*)d_in[18]; const float* slots_sigma = (const float*)d_in[19];
  const float* ni_g = (const float*)d_in[20];    const float* ni_b = (const float*)d_in[21];
  const float* ns_g = (const float*)d_in[22];    const float* ns_b = (const float*)d_in[23];
  const float* q_w = (const float*)d_in[24];     const float* q_b = (const float*)d_in[25];
  const float* k_w = (const float*)d_in[26];     const float* k_b = (const float*)d_in[27];
  const float* v_w = (const float*)d_in[28];     const float* v_b = (const float*)d_in[29];
  const float* gru_wih = (const float*)d_in[30]; const float* gru_whh = (const float*)d_in[31];
  const float* gru_bih = (const float*)d_in[32]; const float* gru_bhh = (const float*)d_in[33];
  const float* res_ln_g = (const float*)d_in[34]; const float* res_ln_b = (const float*)d_in[35];
  const float* res_w1 = (const float*)d_in[36];  const float* res_b1 = (const float*)d_in[37];
  const float* res_w2 = (const float*)d_in[38];  const float* res_b2 = (const float*)d_in[39];
  const float* pe_dec_w = (const float*)d_in[40]; const float* pe_dec_b = (const float*)d_in[41];
  const float* dec_w1 = (const float*)d_in[42];  const float* dec_b1 = (const float*)d_in[43];
  const float* dec_w2 = (const float*)d_in[44];  const float* dec_b2 = (const float*)d_in[45];
  const float* dec_w3 = (const float*)d_in[46];  const float* dec_b3 = (const float*)d_in[47];
  const float* dec_w4 = (const float*)d_in[48];  const float* dec_b4 = (const float*)d_in[49];

  float* ws  = (float*)d_ws;
  float* out = (float*)d_out;
  ushort* wp  = (ushort*)(ws + W_WP);
  ushort* wpm = (ushort*)(ws + W_WPM);

  k_pe_maps<<<dim3(25), 256, 0, stream>>>(pe_enc_w, pe_enc_b, pe_dec_w, pe_dec_b,
                                          ws + W_PEENC, ws + W_PEDEC);

  const size_t WPSTR = 25 * 2 * 64 * 8;
  k_pack<<<dim3(25), 128, 0, stream>>>(enc_w2, wp + 0 * WPSTR, 0);
  k_pack<<<dim3(25), 128, 0, stream>>>(enc_w3, wp + 1 * WPSTR, 0);
  k_pack<<<dim3(25), 128, 0, stream>>>(enc_w4, wp + 2 * WPSTR, 0);
  k_pack<<<dim3(25), 128, 0, stream>>>(dec_w1, wp + 3 * WPSTR, 1);
  k_pack<<<dim3(25), 128, 0, stream>>>(dec_w2, wp + 4 * WPSTR, 1);
  k_pack<<<dim3(25), 128, 0, stream>>>(dec_w3, wp + 5 * WPSTR, 1);
  k_pack_mat<<<dim3(1), 128, 0, stream>>>(mlp_w1, wpm + 0 * 1024);
  k_pack_mat<<<dim3(1), 128, 0, stream>>>(mlp_w2, wpm + 1 * 1024);
  k_pack_mat<<<dim3(1), 128, 0, stream>>>(k_w,   wpm + 2 * 1024);
  k_pack_mat<<<dim3(1), 128, 0, stream>>>(v_w,   wpm + 3 * 1024);
  k_prep_tc<<<dim3(25), 1024, 0, stream>>>(dec_w1, ws + W_TC);

  ushort* base  = (ushort*)(ws + W_BASE);
  ushort* keys  = (ushort*)(ws + W_KEYS);
  ushort* vals  = (ushort*)(ws + W_VALS);
  float*  attnt = ws + W_POOL;
  ushort* E1    = (ushort*)(ws + W_POOL);
  ushort* E2    = (ushort*)(ws + W_POOL + 3276800);

  // base = convT1(pe_dec) + bias (1 img)
  k_conv_mfma<0, false><<<dim3(25, 1), 256, 0, stream>>>(
      ws + W_PEDEC, wp + 3 * WPSTR, dec_b1, base, nullptr, 0);

  // ---------------- encoder ----------------
  k_conv1<<<dim3(25, Bb), 256, 0, stream>>>(in_x, enc_w1, enc_b1, E1);
  k_conv_mfma<1, true><<<dim3(25, Bb), 256, 0, stream>>>(E1, wp + 0 * WPSTR, enc_b2, E2, nullptr, 0);
  k_conv_mfma<1, true><<<dim3(25, Bb), 256, 0, stream>>>(E2, wp + 1 * WPSTR, enc_b3, E1, nullptr, 0);
  k_conv_mfma<1, true><<<dim3(25, Bb), 256, 0, stream>>>(E1, wp + 2 * WPSTR, enc_b4, E2, nullptr, 0);

  k_hstats<<<dim3(25, Bb), 256, 0, stream>>>(E2, ws + W_PEENC, ws + W_LNPART);
  k_statsfin<<<dim3(1), 64, 0, stream>>>(ws + W_LNPART, ws + W_MEANR);
  k_lnmlpkv_mfma<<<dim3(25, Bb), 256, 0, stream>>>(E2, ws + W_PEENC, ws + W_MEANR,
                                                   ln_enc_g, ln_enc_b, wpm,
                                                   mlp_b1, mlp_b2, ni_g, ni_b,
                                                   k_b, v_b, keys, vals);

  // ---------------- slot attention ----------------
  k_init_q<<<dim3(36), 256, 0, stream>>>(slots_mu, slots_sigma, slot_noise,
                                         ns_g, ns_b, q_w, q_b, ws + W_SLOTS, ws + W_Q);
  for (int it = 0; it < 3; ++it) {
    if (it == 2)
      k_dots_upd<true><<<dim3(25, Bb), 256, 0, stream>>>(ws + W_Q, keys, vals, attnt,
                                                         ws + W_APART, ws + W_UP2);
    else
      k_dots_upd<false><<<dim3(25, Bb), 256, 0, stream>>>(ws + W_Q, keys, vals, attnt,
                                                          ws + W_APART, ws + W_UP2);
    k_gru_fused<<<dim3(36), 256, 0, stream>>>(ws + W_UP2, ws + W_APART,
                                              ws + W_SLOTS, ws + W_RSUM, ws + W_Q,
                                              gru_wih, gru_whh, gru_bih, gru_bhh,
                                              res_ln_g, res_ln_b, res_w1, res_b1,
                                              res_w2, res_b2, ns_g, ns_b, q_w, q_b);
  }
  k_attn_out<<<dim3(7200), 256, 0, stream>>>(attnt, ws + W_RSUM, out);
  k_slots_out<<<dim3(36), 256, 0, stream>>>(ws + W_SLOTS, out);

  k_ts<<<dim3(900), 256, 0, stream>>>(ws + W_TC, ws + W_SLOTS, ws + W_TS);

  // ---------------- decoder ----------------
  ushort* XA = (ushort*)(ws + W_POOL);
  ushort* XB = XA + (size_t)96 * 32 * HWp;
  for (int ch = 0; ch < 3; ++ch) {
    int n0 = ch * 96;
    k_conv_mfma<2, true><<<dim3(25, 96), 256, 0, stream>>>(base, wp + 4 * WPSTR, dec_b2, XA,
                                                           ws + W_TS, n0);
    k_conv_pipe<true><<<dim3(25, 48), 256, 0, stream>>>(XA, wp + 5 * WPSTR, dec_b3, XB);
    k_conv4<<<dim3(25, 96), 256, 0, stream>>>(XB, dec_w4, dec_b4,
                                              out + O_RECON, out + O_MASK, n0);
  }

  k_final<<<dim3(25, Bb), 256, 0, stream>>>(out);
}

// Round 16
// 563.918 us; speedup vs baseline: 1.0750x; 1.0750x over previous
//
#include <hip/hip_runtime.h>
#include <cstddef>
#include <cstdint>

// ---------------------------------------------------------------------------
// STSN forward, v14 = v12 (proven 565us) + incremental-index staging in
// k_conv_mfma (removes per-element div/mod-by-20; bit-identical output).
// v13's T14 pipe reverted (broke L3 residency: FETCH 2.2->47MB).
// B=32, H=W=80, C=32, S=9, ITERS=3
// ---------------------------------------------------------------------------

namespace {

constexpr int Bb  = 32;
constexpr int HWp = 6400;
constexpr float SCALEf = 0.17677669529663687f;  // 32^-0.5

// output section offsets (floats)
constexpr size_t O_COMB  = 0;
constexpr size_t O_RECON = 204800;
constexpr size_t O_MASK  = 2048000;
constexpr size_t O_SLOTS = 3891200;
constexpr size_t O_ATTN  = 3900416;

// workspace layout (float offsets)
constexpr size_t W_PEENC = 0;                 // 204800 [hw][c] fp32
constexpr size_t W_PEDEC = 204800;            // 204800 [c][hw] fp32
constexpr size_t W_BASE  = 409600;            // 102400 (bf16 [hw][c])
constexpr size_t W_TC    = 512000;            // 25600
constexpr size_t W_TS    = 537600;            // 230400
constexpr size_t W_WP    = 768000;            // packed conv weights bf16
constexpr size_t W_WPM   = 844800;            // packed 32x32 matrices bf16
constexpr size_t W_LNPART= 846848;            // 1600
constexpr size_t W_MEANR = 848448;            // 64
constexpr size_t W_Q     = 848512;            // 9216
constexpr size_t W_SLOTS = 857728;            // 9216
constexpr size_t W_APART = 866944;            // 7200
constexpr size_t W_RSUM  = 874144;            // 288
constexpr size_t W_UP2   = 874432;            // 230400
constexpr size_t W_KEYS  = 1104832;           // 3276800 (bf16 [b][hw][c])
constexpr size_t W_VALS  = 4381632;           // 3276800 (bf16)
constexpr size_t W_POOL  = 7658432;           // 21456896 floats available
constexpr size_t W_TOTAL = 29115328;          // 116.5 MB
// Pool aliasing: E1/E2 (encoder) | attnt (attention) | XA/XB (decoder)

typedef __attribute__((ext_vector_type(8))) short short8;
typedef __attribute__((ext_vector_type(4))) float f32x4;

__device__ __forceinline__ ushort f2bf(float f) {
  uint u = __builtin_bit_cast(uint, f);
  uint r = (u + 0x7fffu + ((u >> 16) & 1u)) >> 16;   // RNE
  return (ushort)r;
}
__device__ __forceinline__ float bf2f(ushort b) {
  uint u = ((uint)b) << 16;
  return __builtin_bit_cast(float, u);
}
__device__ __forceinline__ void unpk2(uint w, float& a, float& b) {
  a = __builtin_bit_cast(float, w << 16);
  b = __builtin_bit_cast(float, w & 0xffff0000u);
}

__device__ __forceinline__ float lane_ln(float v, int o, const float* __restrict__ g,
                                         const float* __restrict__ b) {
  float s = v;
#pragma unroll
  for (int m = 16; m >= 1; m >>= 1) s += __shfl_xor(s, m);
  float mean = s * (1.f / 32.f);
  float d = v - mean;
  float q = d * d;
#pragma unroll
  for (int m = 16; m >= 1; m >>= 1) q += __shfl_xor(q, m);
  float rstd = rsqrtf(q * (1.f / 32.f) + 1e-5f);
  return d * rstd * g[o] + b[o];
}

// ---------------- positional-embedding maps ---------------------------------

__global__ void k_pe_maps(const float* __restrict__ pew_e, const float* __restrict__ peb_e,
                          const float* __restrict__ pew_d, const float* __restrict__ peb_d,
                          float* __restrict__ pe_enc, float* __restrict__ pe_dec) {
  int hw = blockIdx.x * 256 + threadIdx.x;
  if (hw >= HWp) return;
  int y = hw / 80, x = hw % 80;
  float g0 = y * (1.f / 79.f), g1 = x * (1.f / 79.f);
  float g2 = 1.f - g0, g3 = 1.f - g1;
#pragma unroll
  for (int c = 0; c < 32; ++c) {
    pe_enc[(size_t)hw * 32 + c] = peb_e[c] + g0 * pew_e[c * 4] + g1 * pew_e[c * 4 + 1] +
                                  g2 * pew_e[c * 4 + 2] + g3 * pew_e[c * 4 + 3];
    pe_dec[(size_t)c * HWp + hw] = peb_d[c] + g0 * pew_d[c * 4] + g1 * pew_d[c * 4 + 1] +
                                   g2 * pew_d[c * 4 + 2] + g3 * pew_d[c * 4 + 3];
  }
}

// ---------------- weight packing -------------------------------------------

__global__ void k_pack(const float* __restrict__ w, ushort* __restrict__ dst, int trans) {
  int tap = blockIdx.x;
  int grp = threadIdx.x >> 6, lane = threadIdx.x & 63;
  int ky = tap / 5, kx = tap % 5;
  int m = grp * 16 + (lane & 15);
  int kb = (lane >> 4) * 8;
  ushort* o = dst + ((size_t)(tap * 2 + grp) * 64 + lane) * 8;
#pragma unroll
  for (int j = 0; j < 8; ++j) {
    int k = kb + j;
    float v = trans ? w[(size_t)k * 800 + m * 25 + (4 - ky) * 5 + (4 - kx)]
                    : w[(size_t)m * 800 + k * 25 + ky * 5 + kx];
    o[j] = f2bf(v);
  }
}

// pack a row-major [32][32] matrix (y = x @ W^T form, A[m=o][k=c]) into A-frags
__global__ void k_pack_mat(const float* __restrict__ w, ushort* __restrict__ dst) {
  int grp = threadIdx.x >> 6, lane = threadIdx.x & 63;   // 128 threads
  int m = grp * 16 + (lane & 15), kb = (lane >> 4) * 8;
  ushort* o = dst + ((size_t)(grp * 64 + lane)) * 8;
#pragma unroll
  for (int j = 0; j < 8; ++j) o[j] = f2bf(w[m * 32 + kb + j]);
}

// ---------------- Tc / Ts for algebraic decoder conv1 ------------------------

__global__ void k_prep_tc(const float* __restrict__ w, float* __restrict__ tc) {
  const int rep[5] = {0, 1, 40, 78, 79};
  int cls = blockIdx.x;
  int yc = cls / 5, xc = cls % 5;
  int ci = threadIdx.x >> 5, co = threadIdx.x & 31;
  int yr = rep[yc], xr = rep[xc];
  float s = 0.f;
#pragma unroll
  for (int ky = 0; ky < 5; ++ky) {
    if ((unsigned)(yr + ky - 2) >= 80u) continue;
#pragma unroll
    for (int kx = 0; kx < 5; ++kx) {
      if ((unsigned)(xr + kx - 2) >= 80u) continue;
      s += w[(size_t)ci * 800 + co * 25 + (4 - ky) * 5 + (4 - kx)];
    }
  }
  tc[(size_t)cls * 1024 + ci * 32 + co] = s;
}

__global__ void k_ts(const float* __restrict__ tc, const float* __restrict__ slots,
                     float* __restrict__ ts) {
  int idx = blockIdx.x * 256 + threadIdx.x;
  if (idx >= 288 * 800) return;
  int img = idx / 800, rem = idx % 800;
  int cls = rem >> 5, o = rem & 31;
  float s = 0.f;
#pragma unroll
  for (int ci = 0; ci < 32; ++ci)
    s += tc[(size_t)cls * 1024 + ci * 32 + o] * slots[(size_t)img * 32 + ci];
  ts[idx] = s;
}

// ---------------- MFMA conv (32->32, 5x5, pad 2), 16x16 tile -----------------
// MODE 0: fp32 channel-major input (base precompute). MODE 1: bf16 chlast.
// MODE 2: relu(base[hw][c] + ts[n0+img][cls(hw)][c]) fused dec1.
// Staging uses incremental (r,x) advance (no per-element div/mod); identical
// element order to v12, bit-identical output.

template <int MODE, bool RELU>
__global__ __launch_bounds__(256, 4) void k_conv_mfma(
    const void* __restrict__ in_, const ushort* __restrict__ wp,
    const float* __restrict__ bias, ushort* __restrict__ out_,
    const float* __restrict__ ts, int n0) {
  __shared__ int4 sm[1600];  // 20 rows * 20 px * 4 units of 16B
  const int n = blockIdx.y;
  const int ty = blockIdx.x / 5, tx = blockIdx.x % 5;
  const int t = threadIdx.x;

  {
    const int u = t & 3;
    int px = t >> 2;                 // 0..63
    int r = px / 20, x = px - r * 20;  // one div at entry
#pragma unroll
    for (int k = 0; k < 7; ++k) {
      if (k < 6 || t < 64) {         // element e = t + 256k < 1600
        int gy = ty * 16 + r - 2, gx = tx * 16 + x - 2;
        int4 pk = {0, 0, 0, 0};
        if ((unsigned)gy < 80u && (unsigned)gx < 80u) {
          int hw = gy * 80 + gx;
          if constexpr (MODE == 0) {
            const float* fp = (const float*)in_;
            ushort bb[8];
#pragma unroll
            for (int j = 0; j < 8; ++j)
              bb[j] = f2bf(fp[(size_t)(u * 8 + j) * HWp + hw]);
            pk.x = (int)((uint)bb[0] | ((uint)bb[1] << 16));
            pk.y = (int)((uint)bb[2] | ((uint)bb[3] << 16));
            pk.z = (int)((uint)bb[4] | ((uint)bb[5] << 16));
            pk.w = (int)((uint)bb[6] | ((uint)bb[7] << 16));
          } else if constexpr (MODE == 1) {
            pk = *(const int4*)((const ushort*)in_ + ((size_t)n * HWp + hw) * 32 + u * 8);
          } else {
            int4 bp = *(const int4*)((const ushort*)in_ + (size_t)hw * 32 + u * 8);
            int yc = gy < 2 ? gy : (gy > 77 ? gy - 75 : 2);
            int xc = gx < 2 ? gx : (gx > 77 ? gx - 75 : 2);
            const float* tp = ts + ((size_t)(n0 + n) * 25 + (yc * 5 + xc)) * 32 + u * 8;
            float t0, t1;
            uint* pw = (uint*)&pk;
            const uint* bw = (const uint*)&bp;
#pragma unroll
            for (int h = 0; h < 4; ++h) {
              unpk2(bw[h], t0, t1);
              float f0 = fmaxf(t0 + tp[2 * h], 0.f);
              float f1 = fmaxf(t1 + tp[2 * h + 1], 0.f);
              pw[h] = (uint)f2bf(f0) | ((uint)f2bf(f1) << 16);
            }
          }
        }
        sm[(r * 20 + x) * 4 + (u ^ ((x >> 1) & 3))] = pk;
      }
      // advance by 64 pixels: +3 rows +4 cols (wrap at 20)
      r += 3; x += 4;
      if (x >= 20) { x -= 20; r += 1; }
    }
  }
  __syncthreads();

  const int wv = t >> 6, lane = t & 63;
  const int l15 = lane & 15, lg = lane >> 4;
  const short8* smS = (const short8*)sm;

  f32x4 acc[4][2];
#pragma unroll
  for (int o = 0; o < 4; ++o)
#pragma unroll
    for (int c = 0; c < 2; ++c) acc[o][c] = f32x4{0.f, 0.f, 0.f, 0.f};

#pragma unroll
  for (int dx = 0; dx < 5; ++dx) {
    short8 Adx[5][2];
#pragma unroll
    for (int dy = 0; dy < 5; ++dy) {
      int tap = dy * 5 + dx;
      Adx[dy][0] = *(const short8*)(wp + ((size_t)(tap * 2 + 0) * 64 + lane) * 8);
      Adx[dy][1] = *(const short8*)(wp + ((size_t)(tap * 2 + 1) * 64 + lane) * 8);
    }
    const int xx = l15 + dx;
    const int us = lg ^ ((xx >> 1) & 3);
#pragma unroll
    for (int r8 = 0; r8 < 8; ++r8) {   // r8 = o + dy, valid range 0..7
      short8 Bv = smS[((wv * 4 + r8) * 20 + xx) * 4 + us];
#pragma unroll
      for (int o = 0; o < 4; ++o) {
        int dy = r8 - o;
        if (dy < 0 || dy > 4) continue;
        acc[o][0] = __builtin_amdgcn_mfma_f32_16x16x32_bf16(Adx[dy][0], Bv, acc[o][0], 0, 0, 0);
        acc[o][1] = __builtin_amdgcn_mfma_f32_16x16x32_bf16(Adx[dy][1], Bv, acc[o][1], 0, 0, 0);
      }
    }
  }

  float bv[2][4];
#pragma unroll
  for (int cg = 0; cg < 2; ++cg)
#pragma unroll
    for (int q = 0; q < 4; ++q) bv[cg][q] = bias[cg * 16 + lg * 4 + q];
  const int ybase = ty * 16 + wv * 4, xbase = tx * 16 + l15;
#pragma unroll
  for (int o = 0; o < 4; ++o) {
    size_t px = (size_t)n * HWp + (ybase + o) * 80 + xbase;
#pragma unroll
    for (int cg = 0; cg < 2; ++cg) {
      f32x4 v = acc[o][cg];
      float o0 = v[0] + bv[cg][0], o1 = v[1] + bv[cg][1];
      float o2 = v[2] + bv[cg][2], o3 = v[3] + bv[cg][3];
      if (RELU) {
        o0 = fmaxf(o0, 0.f); o1 = fmaxf(o1, 0.f);
        o2 = fmaxf(o2, 0.f); o3 = fmaxf(o3, 0.f);
      }
      uint2 pk;
      pk.x = (uint)f2bf(o0) | ((uint)f2bf(o1) << 16);
      pk.y = (uint)f2bf(o2) | ((uint)f2bf(o3) << 16);
      *(uint2*)(out_ + px * 32 + cg * 16 + lg * 4) = pk;
    }
  }
}

// ---------------- encoder conv1 ----------------------------------------------

__global__ __launch_bounds__(256) void k_conv1(const float* __restrict__ in,
                                               const float* __restrict__ w,
                                               const float* __restrict__ b,
                                               ushort* __restrict__ out) {
  int hw = blockIdx.x * 256 + threadIdx.x;
  int n = blockIdx.y;
  int y = hw / 80, x = hw % 80;
  float xv[25];
#pragma unroll
  for (int ky = 0; ky < 5; ++ky)
#pragma unroll
    for (int kx = 0; kx < 5; ++kx) {
      int iy = y + ky - 2, ix = x + kx - 2;
      xv[ky * 5 + kx] = ((unsigned)iy < 80u && (unsigned)ix < 80u)
                            ? in[(size_t)n * HWp + iy * 80 + ix] : 0.f;
    }
  float a[32];
#pragma unroll
  for (int co = 0; co < 32; ++co) {
    float s = b[co];
#pragma unroll
    for (int tp = 0; tp < 25; ++tp) s = fmaf(xv[tp], w[co * 25 + tp], s);
    a[co] = fmaxf(s, 0.f);
  }
  ushort* op = out + ((size_t)n * HWp + hw) * 32;
#pragma unroll
  for (int g = 0; g < 4; ++g) {
    uint4 pk;
    pk.x = (uint)f2bf(a[g * 8 + 0]) | ((uint)f2bf(a[g * 8 + 1]) << 16);
    pk.y = (uint)f2bf(a[g * 8 + 2]) | ((uint)f2bf(a[g * 8 + 3]) << 16);
    pk.z = (uint)f2bf(a[g * 8 + 4]) | ((uint)f2bf(a[g * 8 + 5]) << 16);
    pk.w = (uint)f2bf(a[g * 8 + 6]) | ((uint)f2bf(a[g * 8 + 7]) << 16);
    *(uint4*)(op + g * 8) = pk;
  }
}

// ---------------- decoder conv4 (32->2, 3x3, trans) --------------------------

__global__ __launch_bounds__(256) void k_conv4(const ushort* __restrict__ in,
                                               const float* __restrict__ w,
                                               const float* __restrict__ b,
                                               float* __restrict__ outR,
                                               float* __restrict__ outM, int n0) {
  __shared__ float sw[2 * 288];
  for (int e = threadIdx.x; e < 576; e += 256) {
    int co = e / 288, rem = e % 288;
    int tap = rem / 32, ci = rem % 32;
    sw[e] = w[(size_t)(ci * 2 + co) * 9 + 8 - tap];
  }
  __syncthreads();
  int hw = blockIdx.x * 256 + threadIdx.x;
  int nl = blockIdx.y;
  int y = hw / 80, x = hw % 80;
  float a0 = b[0], a1 = b[1];
  const ushort* ip = in + (size_t)nl * HWp * 32;
#pragma unroll
  for (int ky = 0; ky < 3; ++ky) {
#pragma unroll
    for (int kx = 0; kx < 3; ++kx) {
      int iy = y + ky - 1, ix = x + kx - 1;
      if ((unsigned)iy >= 80u || (unsigned)ix >= 80u) continue;
      int tap = ky * 3 + kx;
      const int4* p = (const int4*)(ip + (size_t)(iy * 80 + ix) * 32);
      const float* w0 = sw + tap * 32;
      const float* w1 = sw + 288 + tap * 32;
#pragma unroll
      for (int u = 0; u < 4; ++u) {
        int4 ch = p[u];
        const uint* cw = (const uint*)&ch;
#pragma unroll
        for (int h = 0; h < 4; ++h) {
          float v0, v1;
          unpk2(cw[h], v0, v1);
          int ci = u * 8 + h * 2;
          a0 = fmaf(v0, w0[ci], a0);     a1 = fmaf(v0, w1[ci], a1);
          a0 = fmaf(v1, w0[ci + 1], a0); a1 = fmaf(v1, w1[ci + 1], a1);
        }
      }
    }
  }
  outR[(size_t)(n0 + nl) * HWp + hw] = a0;
  outM[(size_t)(n0 + nl) * HWp + hw] = a1;
}

// ---------------- big-LN stats from E2+PE ------------------------------------

__global__ __launch_bounds__(256) void k_hstats(const ushort* __restrict__ enc,
                                                const float* __restrict__ pe_enc,
                                                float* __restrict__ lnpart) {
  int b = blockIdx.y;
  int hw = blockIdx.x * 256 + threadIdx.x;
  const int4* ep = (const int4*)(enc + ((size_t)b * HWp + hw) * 32);
  float v[32];
#pragma unroll
  for (int u = 0; u < 4; ++u) {
    int4 ch = ep[u];
    const uint* cw = (const uint*)&ch;
#pragma unroll
    for (int h = 0; h < 4; ++h) unpk2(cw[h], v[u * 8 + h * 2], v[u * 8 + h * 2 + 1]);
  }
  float s = 0.f, ss = 0.f;
#pragma unroll
  for (int c = 0; c < 32; ++c) {
    v[c] += pe_enc[(size_t)hw * 32 + c];
    s += v[c]; ss += v[c] * v[c];
  }
  __shared__ float r1[256], r2[256];
  r1[threadIdx.x] = s; r2[threadIdx.x] = ss;
  __syncthreads();
  for (int off = 128; off > 0; off >>= 1) {
    if (threadIdx.x < off) { r1[threadIdx.x] += r1[threadIdx.x + off]; r2[threadIdx.x] += r2[threadIdx.x + off]; }
    __syncthreads();
  }
  if (threadIdx.x == 0) {
    lnpart[(size_t)(b * 25 + blockIdx.x) * 2] = r1[0];
    lnpart[(size_t)(b * 25 + blockIdx.x) * 2 + 1] = r2[0];
  }
}

__global__ void k_statsfin(const float* __restrict__ lnpart, float* __restrict__ meanr) {
  int b = threadIdx.x;
  if (b >= 32) return;
  float s = 0.f, ss = 0.f;
  for (int k = 0; k < 25; ++k) {
    s += lnpart[(size_t)(b * 25 + k) * 2];
    ss += lnpart[(size_t)(b * 25 + k) * 2 + 1];
  }
  float m = s * (1.f / 204800.f);
  float var = ss * (1.f / 204800.f) - m * m;
  meanr[b * 2] = m;
  meanr[b * 2 + 1] = rsqrtf(var + 1e-5f);
}

// ---------------- MFMA lnmlpkv ----------------------------------------------

__global__ __launch_bounds__(256) void k_lnmlpkv_mfma(
    const ushort* __restrict__ enc, const float* __restrict__ pe,
    const float* __restrict__ meanr,
    const float* __restrict__ g, const float* __restrict__ bb,
    const ushort* __restrict__ wm,
    const float* __restrict__ b1, const float* __restrict__ b2,
    const float* __restrict__ nig, const float* __restrict__ nib,
    const float* __restrict__ kb, const float* __restrict__ vb,
    ushort* __restrict__ keys, ushort* __restrict__ vals) {
  __shared__ ushort ls[256 * 32];   // 16 KB bounce buffer
  const int b = blockIdx.y, jb = blockIdx.x;
  const int t = threadIdx.x, wv = t >> 6, lane = t & 63;
  const int l15 = lane & 15, lg = lane >> 4;
  const int skey = l15 & 3;

  short8 A[4][2];
#pragma unroll
  for (int mt = 0; mt < 4; ++mt)
#pragma unroll
    for (int gr = 0; gr < 2; ++gr)
      A[mt][gr] = *(const short8*)(wm + ((size_t)(mt * 2 + gr) * 64 + lane) * 8);

  float4 b1v0 = *(const float4*)(b1 + lg * 4),  b1v1 = *(const float4*)(b1 + 16 + lg * 4);
  float4 b2v0 = *(const float4*)(b2 + lg * 4),  b2v1 = *(const float4*)(b2 + 16 + lg * 4);
  float4 ng0  = *(const float4*)(nig + lg * 4), ng1  = *(const float4*)(nig + 16 + lg * 4);
  float4 nb0  = *(const float4*)(nib + lg * 4), nb1  = *(const float4*)(nib + 16 + lg * 4);
  float4 kbv0 = *(const float4*)(kb + lg * 4),  kbv1 = *(const float4*)(kb + 16 + lg * 4);
  float4 vbv0 = *(const float4*)(vb + lg * 4),  vbv1 = *(const float4*)(vb + 16 + lg * 4);

  const float m_ = meanr[b * 2], rs_ = meanr[b * 2 + 1];

  short8 bx[4];
#pragma unroll
  for (int g2 = 0; g2 < 4; ++g2) {
    int pos = jb * 256 + wv * 64 + g2 * 16 + l15;
    int4 e = *(const int4*)(enc + ((size_t)b * HWp + pos) * 32 + lg * 8);
    float xv[8];
    const uint* ew = (const uint*)&e;
#pragma unroll
    for (int h = 0; h < 4; ++h) unpk2(ew[h], xv[2 * h], xv[2 * h + 1]);
    float4 p0 = *(const float4*)(pe + (size_t)pos * 32 + lg * 8);
    float4 p1 = *(const float4*)(pe + (size_t)pos * 32 + lg * 8 + 4);
    float4 g0 = *(const float4*)(g + (size_t)pos * 32 + lg * 8);
    float4 g1 = *(const float4*)(g + (size_t)pos * 32 + lg * 8 + 4);
    float4 q0 = *(const float4*)(bb + (size_t)pos * 32 + lg * 8);
    float4 q1 = *(const float4*)(bb + (size_t)pos * 32 + lg * 8 + 4);
    float pv[8] = {p0.x, p0.y, p0.z, p0.w, p1.x, p1.y, p1.z, p1.w};
    float gv[8] = {g0.x, g0.y, g0.z, g0.w, g1.x, g1.y, g1.z, g1.w};
    float qv[8] = {q0.x, q0.y, q0.z, q0.w, q1.x, q1.y, q1.z, q1.w};
    uint pk[4];
#pragma unroll
    for (int h = 0; h < 4; ++h) {
      float f0 = (xv[2 * h] + pv[2 * h] - m_) * rs_ * gv[2 * h] + qv[2 * h];
      float f1 = (xv[2 * h + 1] + pv[2 * h + 1] - m_) * rs_ * gv[2 * h + 1] + qv[2 * h + 1];
      pk[h] = (uint)f2bf(f0) | ((uint)f2bf(f1) << 16);
    }
    bx[g2] = __builtin_bit_cast(short8, *(int4*)pk);
  }

  auto lds_write = [&](int posl, int cg, const f32x4& v) {
    int u = cg * 2 + (lg >> 1);
    int us = u ^ skey;
    uint2 pk;
    pk.x = (uint)f2bf(v[0]) | ((uint)f2bf(v[1]) << 16);
    pk.y = (uint)f2bf(v[2]) | ((uint)f2bf(v[3]) << 16);
    *(uint2*)(ls + (size_t)posl * 32 + us * 8 + (lg & 1) * 4) = pk;
  };

#pragma unroll
  for (int g2 = 0; g2 < 4; ++g2) {
    int posl = wv * 64 + g2 * 16 + l15;
    f32x4 a0 = __builtin_amdgcn_mfma_f32_16x16x32_bf16(A[0][0], bx[g2], f32x4{0, 0, 0, 0}, 0, 0, 0);
    f32x4 a1 = __builtin_amdgcn_mfma_f32_16x16x32_bf16(A[0][1], bx[g2], f32x4{0, 0, 0, 0}, 0, 0, 0);
    f32x4 r0, r1;
#pragma unroll
    for (int q = 0; q < 4; ++q) {
      r0[q] = fmaxf(a0[q] + (&b1v0.x)[q], 0.f);
      r1[q] = fmaxf(a1[q] + (&b1v1.x)[q], 0.f);
    }
    lds_write(posl, 0, r0);
    lds_write(posl, 1, r1);
  }
  __syncthreads();
  short8 t0f[4];
#pragma unroll
  for (int g2 = 0; g2 < 4; ++g2) {
    int posl = wv * 64 + g2 * 16 + l15;
    t0f[g2] = *(const short8*)(ls + (size_t)posl * 32 + (lg ^ skey) * 8);
  }
  __syncthreads();

#pragma unroll
  for (int g2 = 0; g2 < 4; ++g2) {
    int posl = wv * 64 + g2 * 16 + l15;
    f32x4 c0 = __builtin_amdgcn_mfma_f32_16x16x32_bf16(A[1][0], t0f[g2], f32x4{0, 0, 0, 0}, 0, 0, 0);
    f32x4 c1 = __builtin_amdgcn_mfma_f32_16x16x32_bf16(A[1][1], t0f[g2], f32x4{0, 0, 0, 0}, 0, 0, 0);
#pragma unroll
    for (int q = 0; q < 4; ++q) { c0[q] += (&b2v0.x)[q]; c1[q] += (&b2v1.x)[q]; }
    float s = 0.f;
#pragma unroll
    for (int q = 0; q < 4; ++q) s += c0[q] + c1[q];
    s += __shfl_xor(s, 16); s += __shfl_xor(s, 32);
    float mean = s * (1.f / 32.f);
    float var = 0.f;
#pragma unroll
    for (int q = 0; q < 4; ++q) {
      float d0 = c0[q] - mean, d1 = c1[q] - mean;
      var += d0 * d0 + d1 * d1;
    }
    var += __shfl_xor(var, 16); var += __shfl_xor(var, 32);
    float rstd = rsqrtf(var * (1.f / 32.f) + 1e-5f);
    f32x4 y0, y1;
#pragma unroll
    for (int q = 0; q < 4; ++q) {
      y0[q] = (c0[q] - mean) * rstd * (&ng0.x)[q] + (&nb0.x)[q];
      y1[q] = (c1[q] - mean) * rstd * (&ng1.x)[q] + (&nb1.x)[q];
    }
    lds_write(posl, 0, y0);
    lds_write(posl, 1, y1);
  }
  __syncthreads();
  short8 xnf[4];
#pragma unroll
  for (int g2 = 0; g2 < 4; ++g2) {
    int posl = wv * 64 + g2 * 16 + l15;
    xnf[g2] = *(const short8*)(ls + (size_t)posl * 32 + (lg ^ skey) * 8);
  }

#pragma unroll
  for (int g2 = 0; g2 < 4; ++g2) {
    int pos = jb * 256 + wv * 64 + g2 * 16 + l15;
    size_t px = ((size_t)b * HWp + pos) * 32;
    f32x4 k0 = __builtin_amdgcn_mfma_f32_16x16x32_bf16(A[2][0], xnf[g2], f32x4{0, 0, 0, 0}, 0, 0, 0);
    f32x4 k1 = __builtin_amdgcn_mfma_f32_16x16x32_bf16(A[2][1], xnf[g2], f32x4{0, 0, 0, 0}, 0, 0, 0);
    f32x4 v0 = __builtin_amdgcn_mfma_f32_16x16x32_bf16(A[3][0], xnf[g2], f32x4{0, 0, 0, 0}, 0, 0, 0);
    f32x4 v1 = __builtin_amdgcn_mfma_f32_16x16x32_bf16(A[3][1], xnf[g2], f32x4{0, 0, 0, 0}, 0, 0, 0);
    uint2 pk;
    pk.x = (uint)f2bf(k0[0] + kbv0.x) | ((uint)f2bf(k0[1] + kbv0.y) << 16);
    pk.y = (uint)f2bf(k0[2] + kbv0.z) | ((uint)f2bf(k0[3] + kbv0.w) << 16);
    *(uint2*)(keys + px + lg * 4) = pk;
    pk.x = (uint)f2bf(k1[0] + kbv1.x) | ((uint)f2bf(k1[1] + kbv1.y) << 16);
    pk.y = (uint)f2bf(k1[2] + kbv1.z) | ((uint)f2bf(k1[3] + kbv1.w) << 16);
    *(uint2*)(keys + px + 16 + lg * 4) = pk;
    pk.x = (uint)f2bf(v0[0] + vbv0.x) | ((uint)f2bf(v0[1] + vbv0.y) << 16);
    pk.y = (uint)f2bf(v0[2] + vbv0.z) | ((uint)f2bf(v0[3] + vbv0.w) << 16);
    *(uint2*)(vals + px + lg * 4) = pk;
    pk.x = (uint)f2bf(v1[0] + vbv1.x) | ((uint)f2bf(v1[1] + vbv1.y) << 16);
    pk.y = (uint)f2bf(v1[2] + vbv1.z) | ((uint)f2bf(v1[3] + vbv1.w) << 16);
    *(uint2*)(vals + px + 16 + lg * 4) = pk;
  }
}

// ---------------- slot attention -------------------------------------------

__global__ __launch_bounds__(256) void k_init_q(
    const float* __restrict__ mu, const float* __restrict__ sig,
    const float* __restrict__ noise,
    const float* __restrict__ nsg, const float* __restrict__ nsb,
    const float* __restrict__ qw, const float* __restrict__ qb,
    float* __restrict__ slots, float* __restrict__ qbuf) {
  int rl = threadIdx.x >> 5, o = threadIdx.x & 31;
  int r = blockIdx.x * 8 + rl;
  float s = mu[o] + sig[o] * noise[(size_t)r * 32 + o];
  slots[(size_t)r * 32 + o] = s;
  float y = lane_ln(s, o, nsg, nsb);
  __shared__ float S[8][32];
  S[rl][o] = y;
  __syncthreads();
  float qv = qb[o];
#pragma unroll
  for (int c = 0; c < 32; ++c) qv = fmaf(S[rl][c], qw[o * 32 + c], qv);
  qbuf[(size_t)r * 32 + o] = qv;
}

template <bool LAST>
__global__ __launch_bounds__(256) void k_dots_upd(
    const float* __restrict__ qbuf, const ushort* __restrict__ keys,
    const ushort* __restrict__ vals, float* __restrict__ attnt,
    float* __restrict__ apart, float* __restrict__ up2) {
  int b = blockIdx.y, jb = blockIdx.x;
  int t = threadIdx.x;
  int j = jb * 256 + t;
  __shared__ float qs[288];
  __shared__ float aL[2304];
  __shared__ float wr[36];
  for (int e = t; e < 288; e += 256) qs[e] = qbuf[(size_t)b * 288 + e];
  __syncthreads();
  float k[32];
  const int4* kp = (const int4*)(keys + ((size_t)b * HWp + j) * 32);
#pragma unroll
  for (int u = 0; u < 4; ++u) {
    int4 ch = kp[u];
    const uint* cw = (const uint*)&ch;
#pragma unroll
    for (int h = 0; h < 4; ++h) unpk2(cw[h], k[u * 8 + h * 2], k[u * 8 + h * 2 + 1]);
  }
  float d[9];
#pragma unroll
  for (int i = 0; i < 9; ++i) {
    float a = 0.f;
#pragma unroll
    for (int c = 0; c < 32; ++c) a = fmaf(qs[i * 32 + c], k[c], a);
    d[i] = a * SCALEf;
  }
  float mx = d[0];
#pragma unroll
  for (int i = 1; i < 9; ++i) mx = fmaxf(mx, d[i]);
  float sum = 0.f;
#pragma unroll
  for (int i = 0; i < 9; ++i) { d[i] = __expf(d[i] - mx); sum += d[i]; }
  float inv = 1.f / sum;
  float a9[9];
#pragma unroll
  for (int i = 0; i < 9; ++i) {
    a9[i] = d[i] * inv + 1e-8f;
    if (LAST) attnt[((size_t)b * 9 + i) * HWp + j] = a9[i];
    aL[t * 9 + i] = a9[i];
  }
  int lane = t & 63, wid = t >> 6;
#pragma unroll
  for (int i = 0; i < 9; ++i) {
    float v = a9[i];
    for (int off = 32; off > 0; off >>= 1) v += __shfl_down(v, off);
    if (lane == 0) wr[wid * 9 + i] = v;
  }
  __syncthreads();
  if (t < 9)
    apart[(size_t)(b * 9 + t) * 25 + jb] = wr[t] + wr[9 + t] + wr[18 + t] + wr[27 + t];
  int c = t & 31, g = t >> 5;
  float acc[9];
#pragma unroll
  for (int i = 0; i < 9; ++i) acc[i] = 0.f;
  const ushort* vp = vals + ((size_t)b * HWp + jb * 256) * 32 + c;
  for (int jj = g; jj < 256; jj += 8) {
    float v = bf2f(vp[(size_t)jj * 32]);
#pragma unroll
    for (int i = 0; i < 9; ++i) acc[i] = fmaf(v, aL[jj * 9 + i], acc[i]);
  }
  __syncthreads();
#pragma unroll
  for (int i = 0; i < 9; ++i) aL[(i * 8 + g) * 32 + c] = acc[i];
  __syncthreads();
  for (int i = g; i < 9; i += 8) {
    float s = 0.f;
#pragma unroll
    for (int g2 = 0; g2 < 8; ++g2) s += aL[(i * 8 + g2) * 32 + c];
    up2[(((size_t)b * 25 + jb) * 9 + i) * 32 + c] = s;
  }
}

__global__ __launch_bounds__(256) void k_gru_fused(
    const float* __restrict__ up2, const float* __restrict__ apart,
    float* __restrict__ slots, float* __restrict__ rowsum, float* __restrict__ qbuf,
    const float* __restrict__ wih, const float* __restrict__ whh,
    const float* __restrict__ bih, const float* __restrict__ bhh,
    const float* __restrict__ rlg, const float* __restrict__ rlb,
    const float* __restrict__ rw1, const float* __restrict__ rb1,
    const float* __restrict__ rw2, const float* __restrict__ rb2,
    const float* __restrict__ nsg, const float* __restrict__ nsb,
    const float* __restrict__ qw, const float* __restrict__ qb) {
  int rl = threadIdx.x >> 5, o = threadIdx.x & 31;
  int r = blockIdx.x * 8 + rl;
  int b = r / 9, i = r - b * 9;

  float rs = 0.f;
#pragma unroll
  for (int k = 0; k < 25; ++k) rs += apart[(size_t)(b * 9 + i) * 25 + k];
  if (o == 0) rowsum[r] = rs;

  float uo = 0.f;
#pragma unroll
  for (int jc = 0; jc < 25; ++jc) uo += up2[(((size_t)b * 25 + jc) * 9 + i) * 32 + o];
  uo /= rs;
  float ho = slots[(size_t)r * 32 + o];

  __shared__ float Us[8][32], Hs[8][32];
  Us[rl][o] = uo; Hs[rl][o] = ho;
  __syncthreads();

  float xr = bih[o], xz = bih[32 + o], xc = bih[64 + o];
  float hr = bhh[o], hz = bhh[32 + o], hc = bhh[64 + o];
#pragma unroll
  for (int c = 0; c < 32; ++c) {
    float u = Us[rl][c], h = Hs[rl][c];
    xr = fmaf(u, wih[o * 32 + c], xr);          hr = fmaf(h, whh[o * 32 + c], hr);
    xz = fmaf(u, wih[(32 + o) * 32 + c], xz);   hz = fmaf(h, whh[(32 + o) * 32 + c], hz);
    xc = fmaf(u, wih[(64 + o) * 32 + c], xc);   hc = fmaf(h, whh[(64 + o) * 32 + c], hc);
  }
  float rr = 1.f / (1.f + __expf(-(xr + hr)));
  float zz = 1.f / (1.f + __expf(-(xz + hz)));
  float cand = tanhf(xc + rr * hc);
  float sm = (1.f - zz) * cand + zz * ho;

  float y = lane_ln(sm, o, rlg, rlb);
  __syncthreads();
  Us[rl][o] = y;
  __syncthreads();
  float t1 = rb1[o];
#pragma unroll
  for (int c = 0; c < 32; ++c) t1 = fmaf(Us[rl][c], rw1[o * 32 + c], t1);
  t1 = fmaxf(t1, 0.f);
  Hs[rl][o] = t1;
  __syncthreads();
  float res = rb2[o];
#pragma unroll
  for (int c = 0; c < 32; ++c) res = fmaf(Hs[rl][c], rw2[o * 32 + c], res);
  float ns = sm + res;
  slots[(size_t)r * 32 + o] = ns;

  float y2 = lane_ln(ns, o, nsg, nsb);
  __syncthreads();
  Us[rl][o] = y2;
  __syncthreads();
  float qv = qb[o];
#pragma unroll
  for (int c = 0; c < 32; ++c) qv = fmaf(Us[rl][c], qw[o * 32 + c], qv);
  qbuf[(size_t)r * 32 + o] = qv;
}

// ---------------- outputs ----------------------------------------------------

__global__ void k_attn_out(const float* __restrict__ attnt, const float* __restrict__ rsum,
                           float* __restrict__ out) {
  size_t idx = (size_t)blockIdx.x * 256 + threadIdx.x;
  out[O_ATTN + idx] = attnt[idx] / rsum[idx / HWp];
}

__global__ void k_slots_out(const float* __restrict__ slots, float* __restrict__ out) {
  int idx = blockIdx.x * 256 + threadIdx.x;
  if (idx < 9216) out[O_SLOTS + idx] = slots[idx];
}

__global__ __launch_bounds__(256) void k_final(float* __restrict__ out) {
  int b = blockIdx.y;
  int j = blockIdx.x * 256 + threadIdx.x;
  float r[9], ml[9];
#pragma unroll
  for (int s = 0; s < 9; ++s) {
    r[s]  = out[O_RECON + (size_t)(b * 9 + s) * HWp + j];
    ml[s] = out[O_MASK  + (size_t)(b * 9 + s) * HWp + j];
  }
  float mx = ml[0];
#pragma unroll
  for (int s = 1; s < 9; ++s) mx = fmaxf(mx, ml[s]);
  float sum = 0.f;
#pragma unroll
  for (int s = 0; s < 9; ++s) { ml[s] = __expf(ml[s] - mx); sum += ml[s]; }
  float inv = 1.f / sum;
  float comb = 0.f;
#pragma unroll
  for (int s = 0; s < 9; ++s) {
    float mk = ml[s] * inv;
    comb = fmaf(r[s], mk, comb);
    out[O_MASK + (size_t)(b * 9 + s) * HWp + j] = mk;
  }
  out[O_COMB + (size_t)b * HWp + j] = comb;
}

}  // namespace

// ---------------------------------------------------------------------------

extern "C" void kernel_launch(void* const* d_in, const int* in_sizes, int n_in,
                              void* d_out, int out_size, void* d_ws, size_t ws_size,
                              hipStream_t stream) {
  if (ws_size < W_TOTAL * sizeof(float)) return;

  const float* in_x       = (const float*)d_in[0];
  const float* slot_noise = (const float*)d_in[1];
  const float* enc_w1 = (const float*)d_in[2];   const float* enc_b1 = (const float*)d_in[3];
  const float* enc_w2 = (const float*)d_in[4];   const float* enc_b2 = (const float*)d_in[5];
  const float* enc_w3 = (const float*)d_in[6];   const float* enc_b3 = (const float*)d_in[7];
  const float* enc_w4 = (const float*)d_in[8];   const float* enc_b4 = (const float*)d_in[9];
  const float* pe_enc_w = (const float*)d_in[10]; const float* pe_enc_b = (const float*)d_in[11];
  const float* ln_enc_g = (const float*)d_in[12]; const float* ln_enc_b = (const float*)d_in[13];
  const float* mlp_w1 = (const float*)d_in[14];  const float* mlp_b1 = (const float*)d_in[15];
  const float* mlp_w2 = (const float*)d_in[16];  const float* mlp_b2 = (const float*)d_in[17];
  const float* slots_mu = (const float*)d_in[18]; const float* slots_sigma = (const float*)d_in[19];
  const float* ni_g = (const float*)d_in[20];    const float* ni_b = (const float*)d_in[21];
  const float* ns_g = (const float*)d_in[22];    const float* ns_b = (const float*)d_in[23];
  const float* q_w = (const float*)d_in[24];     const float* q_b = (const float*)d_in[25];
  const float* k_w = (const float*)d_in[26];     const float* k_b = (const float*)d_in[27];
  const float* v_w = (const float*)d_in[28];     const float* v_b = (const float*)d_in[29];
  const float* gru_wih = (const float*)d_in[30]; const float* gru_whh = (const float*)d_in[31];
  const float* gru_bih = (const float*)d_in[32]; const float* gru_bhh = (const float*)d_in[33];
  const float* res_ln_g = (const float*)d_in[34]; const float* res_ln_b = (const float*)d_in[35];
  const float* res_w1 = (const float*)d_in[36];  const float* res_b1 = (const float*)d_in[37];
  const float* res_w2 = (const float*)d_in[38];  const float* res_b2 = (const float*)d_in[39];
  const float* pe_dec_w = (const float*)d_in[40]; const float* pe_dec_b = (const float*)d_in[41];
  const float* dec_w1 = (const float*)d_in[42];  const float* dec_b1 = (const float*)d_in[43];
  const float* dec_w2 = (const float*)d_in[44];  const float* dec_b2 = (const float*)d_in[45];
  const float* dec_w3 = (const float*)d_in[46];  const float* dec_b3 = (const float*)d_in[47];
  const float* dec_w4 = (const float*)d_in[48];  const float* dec_b4 = (const float*)d_in[49];

  float* ws  = (float*)d_ws;
  float* out = (float*)d_out;
  ushort* wp  = (ushort*)(ws + W_WP);
  ushort* wpm = (ushort*)(ws + W_WPM);

  k_pe_maps<<<dim3(25), 256, 0, stream>>>(pe_enc_w, pe_enc_b, pe_dec_w, pe_dec_b,
                                          ws + W_PEENC, ws + W_PEDEC);

  const size_t WPSTR = 25 * 2 * 64 * 8;
  k_pack<<<dim3(25), 128, 0, stream>>>(enc_w2, wp + 0 * WPSTR, 0);
  k_pack<<<dim3(25), 128, 0, stream>>>(enc_w3, wp + 1 * WPSTR, 0);
  k_pack<<<dim3(25), 128, 0, stream>>>(enc_w4, wp + 2 * WPSTR, 0);
  k_pack<<<dim3(25), 128, 0, stream>>>(dec_w1, wp + 3 * WPSTR, 1);
  k_pack<<<dim3(25), 128, 0, stream>>>(dec_w2, wp + 4 * WPSTR, 1);
  k_pack<<<dim3(25), 128, 0, stream>>>(dec_w3, wp + 5 * WPSTR, 1);
  k_pack_mat<<<dim3(1), 128, 0, stream>>>(mlp_w1, wpm + 0 * 1024);
  k_pack_mat<<<dim3(1), 128, 0, stream>>>(mlp_w2, wpm + 1 * 1024);
  k_pack_mat<<<dim3(1), 128, 0, stream>>>(k_w,   wpm + 2 * 1024);
  k_pack_mat<<<dim3(1), 128, 0, stream>>>(v_w,   wpm + 3 * 1024);
  k_prep_tc<<<dim3(25), 1024, 0, stream>>>(dec_w1, ws + W_TC);

  ushort* base  = (ushort*)(ws + W_BASE);
  ushort* keys  = (ushort*)(ws + W_KEYS);
  ushort* vals  = (ushort*)(ws + W_VALS);
  float*  attnt = ws + W_POOL;
  ushort* E1    = (ushort*)(ws + W_POOL);
  ushort* E2    = (ushort*)(ws + W_POOL + 3276800);

  // base = convT1(pe_dec) + bias (1 img)
  k_conv_mfma<0, false><<<dim3(25, 1), 256, 0, stream>>>(
      ws + W_PEDEC, wp + 3 * WPSTR, dec_b1, base, nullptr, 0);

  // ---------------- encoder ----------------
  k_conv1<<<dim3(25, Bb), 256, 0, stream>>>(in_x, enc_w1, enc_b1, E1);
  k_conv_mfma<1, true><<<dim3(25, Bb), 256, 0, stream>>>(E1, wp + 0 * WPSTR, enc_b2, E2, nullptr, 0);
  k_conv_mfma<1, true><<<dim3(25, Bb), 256, 0, stream>>>(E2, wp + 1 * WPSTR, enc_b3, E1, nullptr, 0);
  k_conv_mfma<1, true><<<dim3(25, Bb), 256, 0, stream>>>(E1, wp + 2 * WPSTR, enc_b4, E2, nullptr, 0);

  k_hstats<<<dim3(25, Bb), 256, 0, stream>>>(E2, ws + W_PEENC, ws + W_LNPART);
  k_statsfin<<<dim3(1), 64, 0, stream>>>(ws + W_LNPART, ws + W_MEANR);
  k_lnmlpkv_mfma<<<dim3(25, Bb), 256, 0, stream>>>(E2, ws + W_PEENC, ws + W_MEANR,
                                                   ln_enc_g, ln_enc_b, wpm,
                                                   mlp_b1, mlp_b2, ni_g, ni_b,
                                                   k_b, v_b, keys, vals);

  // ---------------- slot attention ----------------
  k_init_q<<<dim3(36), 256, 0, stream>>>(slots_mu, slots_sigma, slot_noise,
                                         ns_g, ns_b, q_w, q_b, ws + W_SLOTS, ws + W_Q);
  for (int it = 0; it < 3; ++it) {
    if (it == 2)
      k_dots_upd<true><<<dim3(25, Bb), 256, 0, stream>>>(ws + W_Q, keys, vals, attnt,
                                                         ws + W_APART, ws + W_UP2);
    else
      k_dots_upd<false><<<dim3(25, Bb), 256, 0, stream>>>(ws + W_Q, keys, vals, attnt,
                                                          ws + W_APART, ws + W_UP2);
    k_gru_fused<<<dim3(36), 256, 0, stream>>>(ws + W_UP2, ws + W_APART,
                                              ws + W_SLOTS, ws + W_RSUM, ws + W_Q,
                                              gru_wih, gru_whh, gru_bih, gru_bhh,
                                              res_ln_g, res_ln_b, res_w1, res_b1,
                                              res_w2, res_b2, ns_g, ns_b, q_w, q_b);
  }
  k_attn_out<<<dim3(7200), 256, 0, stream>>>(attnt, ws + W_RSUM, out);
  k_slots_out<<<dim3(36), 256, 0, stream>>>(ws + W_SLOTS, out);

  k_ts<<<dim3(900), 256, 0, stream>>>(ws + W_TC, ws + W_SLOTS, ws + W_TS);

  // ---------------- decoder ----------------
  ushort* XA = (ushort*)(ws + W_POOL);
  ushort* XB = XA + (size_t)96 * 32 * HWp;
  for (int ch = 0; ch < 3; ++ch) {
    int n0 = ch * 96;
    k_conv_mfma<2, true><<<dim3(25, 96), 256, 0, stream>>>(base, wp + 4 * WPSTR, dec_b2, XA,
                                                           ws + W_TS, n0);
    k_conv_mfma<1, true><<<dim3(25, 96), 256, 0, stream>>>(XA, wp + 5 * WPSTR, dec_b3, XB,
                                                           nullptr, 0);
    k_conv4<<<dim3(25, 96), 256, 0, stream>>>(XB, dec_w4, dec_b4,
                                              out + O_RECON, out + O_MASK, n0);
  }

  k_final<<<dim3(25, Bb), 256, 0, stream>>>(out);
}